// Round 13
// baseline (632.228 us; speedup 1.0000x reference)
//
#include <hip/hip_runtime.h>
#include <hip/hip_bf16.h>

typedef unsigned int u32;
typedef unsigned short u16;
typedef __bf16 bf16_t;
typedef bf16_t bf16x8 __attribute__((ext_vector_type(8)));
typedef float f32x4 __attribute__((ext_vector_type(4)));

constexpr int NN = 50000;
constexpr int EE = 500000;
constexpr int RR = 8;
constexpr int NKEY = RR * NN;               // 400000
constexpr int PAIR_B = (NKEY + 511) / 512;  // 782

// wext element offsets (bf16 elems)
constexpr int WX_A1T = 0;       // [64][128]
constexpr int WX_C1T = 8192;    // [128][256]
constexpr int WX_C2T = 40960;   // [128][128]
constexpr int WX_A2  = 57344;   // [64]
constexpr int WX_a1  = 57408;   // [64]
constexpr int WX_c1  = 57472;   // [128]
constexpr int WX_c2  = 57600;   // [128]
constexpr int WX_a2s = 57728;   // [1]
constexpr int WX_TOT = 57729;

__device__ __forceinline__ float bf2f(u32 v){
  union { u32 u; float f; } x; x.u = (v & 0xFFFFu) << 16; return x.f;
}
__device__ __forceinline__ u16 f2bf(float f){
  union { u32 u; float f; } x; x.f = f;
  u32 r = x.u + 0x7FFFu + ((x.u >> 16) & 1u);
  return (u16)(r >> 16);
}
__device__ __forceinline__ float lrelu(float x){ return x > 0.f ? x : 0.1f * x; }
__device__ __forceinline__ float ldf(const void* p, int i, u32 fm){
  return fm ? ((const float*)p)[i] : bf2f(((const u16*)p)[i]);
}
// direct global->LDS DMA, 16B per lane; LDS dest is wave-uniform base + lane*16
__device__ __forceinline__ void gl_lds16(const u16* g, u16* l){
  __builtin_amdgcn_global_load_lds((const __attribute__((address_space(1))) u32*)g,
                                   (__attribute__((address_space(3))) u32*)l, 16, 0, 0);
}
__device__ __forceinline__ bf16x8 cvt8(float4 a, float4 b){
  union { bf16x8 v; u16 s[8]; } r;
  r.s[0]=f2bf(a.x); r.s[1]=f2bf(a.y); r.s[2]=f2bf(a.z); r.s[3]=f2bf(a.w);
  r.s[4]=f2bf(b.x); r.s[5]=f2bf(b.y); r.s[6]=f2bf(b.z); r.s[7]=f2bf(b.w);
  return r.v;
}

// ---------------- dtype detectors ----------------
__global__ void k_fdetect(const void* x, u32* md){
  __shared__ u32 c;
  if (threadIdx.x == 0) c = 0;
  __syncthreads();
  const u16* p = (const u16*)x;
  u32 loc = 0;
  for (int j = 0; j < 16; j++){
    u16 v = p[threadIdx.x * 16 + j];
    u32 e = (v >> 7) & 0xFF;
    if (e >= 0xFD) loc++;
  }
  atomicAdd(&c, loc);
  __syncthreads();
  if (threadIdx.x == 0) md[0] = (c >= 4) ? 1u : 0u;
}
__global__ void k_idetect(const void* et, u32* md){
  __shared__ u32 c;
  if (threadIdx.x == 0) c = 0;
  __syncthreads();
  const int* p = (const int*)et;
  u32 loc = 0;
  for (int j = 0; j < 8; j++){
    int idx = 2 * (threadIdx.x * 8 + j) + 1;
    if (p[idx] != 0) loc++;
  }
  atomicAdd(&c, loc);
  __syncthreads();
  if (threadIdx.x == 0) md[1] = (c == 0) ? 1u : 0u;
}

// ---------------- int conversion -> int32 ws copies (+fused (dst,rel) count)
__global__ void k_icvt(const void* ei, const void* et, const void* bat,
                       int* ei_c, int* et_c, int* bat_c, u32* __restrict__ cnt,
                       const u32* md){
  u32 im = md[1];
  int i = blockIdx.x * 256 + threadIdx.x;
  if (i < EE){
    const int* p = (const int*)ei;
    ei_c[i] = im ? p[2 * i] : p[i];
  } else if (i < 2 * EE){
    int j = i - EE;
    const int* p = (const int*)ei;
    const int* pt = (const int*)et;
    int d = im ? p[2 * i] : p[i];
    int r = im ? pt[2 * j] : pt[j];
    ei_c[i] = d;
    atomicAdd(&cnt[d * RR + r], 1u);
  } else if (i < 3 * EE){
    int j = i - 2 * EE;
    const int* p = (const int*)et;
    et_c[j] = im ? p[2 * j] : p[j];
  } else if (i < 3 * EE + NN){
    int j = i - 3 * EE;
    const int* p = (const int*)bat;
    bat_c[j] = im ? p[2 * j] : p[j];
  }
}

// ---------------- x conversion -> bf16 ws copy (+NaN flag bit1)
__global__ void k_xcvt(const void* x, u16* xb, const u32* md, u32* flags){
  u32 fm = md[0];
  int i4 = (blockIdx.x * 256 + threadIdx.x) * 4;
  if (i4 >= NN * 128) return;
  float v[4];
  if (fm){
    float4 f = *(const float4*)((const float*)x + i4);
    v[0]=f.x; v[1]=f.y; v[2]=f.z; v[3]=f.w;
  } else {
    uint2 u = *(const uint2*)((const u16*)x + i4);
    v[0]=bf2f(u.x); v[1]=bf2f(u.x>>16); v[2]=bf2f(u.y); v[3]=bf2f(u.y>>16);
  }
  bool bad = false;
  u16 o[4];
  for (int j = 0; j < 4; j++){
    if (v[j] != v[j]){ bad = true; v[j] = 0.f; }
    o[j] = f2bf(v[j]);
  }
  unsigned long long bal = __ballot(bad);
  if (bal && (threadIdx.x & 63) == 0) atomicOr(flags, 2u);
  uint2 st;
  st.x = (u32)o[0] | ((u32)o[1] << 16);
  st.y = (u32)o[2] | ((u32)o[3] << 16);
  *(uint2*)(xb + i4) = st;
}

// ---------------- weight transpose: wcatT[L][n][k']
// k'<1024: k' = c*8 + r  ->  W[L][r*128+c][n]   (matches k_agg's [c][r] agg layout)
// k'>=1024: root[k'-1024][n]
__global__ void k_wcat(const void* W1, const void* r1, const void* W2, const void* r2,
                       const void* W3, const void* r3, u16* wcatT, const u32* md, u32* flags){
  u32 fm = md[0];
  int idx = blockIdx.x * 256 + threadIdx.x;
  if (idx >= 3 * 128 * 1152) return;
  int L = idx / (128 * 1152);
  int rem = idx % (128 * 1152);
  int n = rem / 1152, k = rem % 1152;
  const void* W  = (L == 0) ? W1 : ((L == 1) ? W2 : W3);
  const void* rt = (L == 0) ? r1 : ((L == 1) ? r2 : r3);
  float v;
  if (k < 1024){
    int r = k & 7, c = k >> 3;
    v = ldf(W, (r * 128 + c) * 128 + n, fm);
  } else {
    v = ldf(rt, (k - 1024) * 128 + n, fm);
  }
  if (v != v){ v = 0.f; atomicOr(flags, 2u); }
  wcatT[idx] = f2bf(v);
}

// ---------------- small-MLP weight prep
__global__ void k_wext(const void* A1, const void* a1, const void* A2, const void* a2,
                       const void* C1, const void* c1, const void* C2, const void* c2,
                       u16* wext, const u32* md){
  u32 fm = md[0];
  int idx = blockIdx.x * 256 + threadIdx.x;
  if (idx >= WX_TOT) return;
  float v;
  if (idx < WX_C1T){
    int n = idx >> 7, k = idx & 127;
    v = ldf(A1, k * 64 + n, fm);
  } else if (idx < WX_C2T){
    int j = idx - WX_C1T; int n = j >> 8, k = j & 255;
    v = ldf(C1, k * 128 + n, fm);
  } else if (idx < WX_A2){
    int j = idx - WX_C2T; int n = j >> 7, k = j & 127;
    v = ldf(C2, k * 128 + n, fm);
  } else if (idx < WX_a1){ v = ldf(A2, idx - WX_A2, fm); }
  else if (idx < WX_c1){ v = ldf(a1, idx - WX_a1, fm); }
  else if (idx < WX_c2){ v = ldf(c1, idx - WX_c1, fm); }
  else if (idx < WX_a2s){ v = ldf(c2, idx - WX_c2, fm); }
  else { v = ldf(a2, 0, fm); }
  wext[idx] = f2bf(v);
}

// ---------------- (dst,rel) counting sort: key = d*RR + r (dst-major) ----------------
__global__ void k_pairA(const u32* __restrict__ cnt, u32* __restrict__ blockSum){
  __shared__ u32 sd[256];
  int b = blockIdx.x, t = threadIdx.x;
  u32 s = 0;
  for (int j = 0; j < 2; j++){
    int key = b * 512 + t * 2 + j;
    if (key < NKEY) s += cnt[key];
  }
  sd[t] = s; __syncthreads();
  for (int off = 128; off; off >>= 1){ if (t < off) sd[t] += sd[t + off]; __syncthreads(); }
  if (t == 0) blockSum[b] = sd[0];
}
__global__ void k_pairB(const u32* __restrict__ blockSum, u32* __restrict__ blockBase){
  int lane = threadIdx.x;   // 64
  u32 loc[13]; u32 s = 0;
  for (int j = 0; j < 13; j++){
    int b = lane * 13 + j;
    u32 v = (b < PAIR_B) ? blockSum[b] : 0u;
    loc[j] = s; s += v;
  }
  u32 tot = s;
  for (int off = 1; off < 64; off <<= 1){
    u32 x = __shfl_up(tot, off);
    if (lane >= off) tot += x;
  }
  u32 excl = tot - s;
  for (int j = 0; j < 13; j++){
    int b = lane * 13 + j;
    if (b < PAIR_B) blockBase[b] = excl + loc[j];
  }
}
__global__ void k_pairC(const u32* __restrict__ cnt, const u32* __restrict__ blockBase,
                        u32* __restrict__ pairStart, u32* __restrict__ cursor){
  __shared__ u32 sd[256];
  int b = blockIdx.x, t = threadIdx.x;
  int k0 = b * 512 + t * 2;
  u32 v0 = 0, v1 = 0;
  if (k0 < NKEY) v0 = cnt[k0];
  if (k0 + 1 < NKEY) v1 = cnt[k0 + 1];
  sd[t] = v0 + v1; __syncthreads();
  for (int off = 1; off < 256; off <<= 1){
    u32 x = (t >= off) ? sd[t - off] : 0u;
    __syncthreads();
    sd[t] += x;
    __syncthreads();
  }
  u32 excl = sd[t] - (v0 + v1);
  u32 base = blockBase[b] + excl;
  if (k0 < NKEY){ pairStart[k0] = base; cursor[k0] = 0u; }
  if (k0 + 1 < NKEY){ pairStart[k0 + 1] = base + v0; cursor[k0 + 1] = 0u; }
  if (k0 + 1 == NKEY - 1) pairStart[NKEY] = base + v0 + v1;   // genuine scan total
}
__global__ void k_sort3(const int* __restrict__ ei, const int* __restrict__ et,
                        const u32* __restrict__ pairStart, u32* __restrict__ cursor,
                        u32* __restrict__ src_s){
  int e = blockIdx.x * 256 + threadIdx.x;
  if (e >= EE) return;
  int r = et[e], d = ei[EE + e];
  u32 key = (u32)d * RR + (u32)r;
  u32 p = pairStart[key] + atomicAdd(&cursor[key], 1u);
  src_s[p] = (u32)ei[e];
}

// ---------------- aggregation: one wave per dst node, all 8 relations
// agg layout: [d][c][r] (elem = c*8+r). Preloaded src broadcast + unroll-2 gather;
// per-lane 2 cols x 8 rel -> one 32B contiguous store (2KB/node coalesced).
__global__ __launch_bounds__(256) void k_agg(const u16* __restrict__ h,
                                             const u32* __restrict__ pairStart,
                                             const u32* __restrict__ src_s,
                                             u16* __restrict__ agg){
  int d = blockIdx.x * 4 + (threadIdx.x >> 6);
  if (d >= NN) return;
  int lane = threadIdx.x & 63;
  const uint4* p4 = (const uint4*)(pairStart + d * 8);
  uint4 q0 = p4[0], q1 = p4[1];
  u32 ps[9];
  ps[0]=q0.x; ps[1]=q0.y; ps[2]=q0.z; ps[3]=q0.w;
  ps[4]=q1.x; ps[5]=q1.y; ps[6]=q1.z; ps[7]=q1.w;
  ps[8]=pairStart[d * 8 + 8];
  u32 jb = ps[0], je = ps[8];
  // coalesced preload of up to 64 src indices for the whole node
  u32 pre = 0;
  if (jb + lane < je) pre = src_s[jb + lane];
  const u16* hb = h + lane * 2;
  u32 ou[8] = {0,0,0,0,0,0,0,0};
  #pragma unroll
  for (int r = 0; r < 8; r++){
    u32 s = ps[r], e = ps[r + 1];
    float a0 = 0.f, a1 = 0.f, b0 = 0.f, b1 = 0.f;
    u32 j = s;
    for (; j + 1 < e; j += 2){
      u32 i0 = j - jb;
      u32 s0 = (i0 < 64) ? __shfl(pre, (int)i0) : src_s[j];
      u32 s1 = (i0 + 1 < 64) ? __shfl(pre, (int)(i0 + 1)) : src_s[j + 1];
      u32 v0 = *(const u32*)(hb + (size_t)s0 * 128);
      u32 v1 = *(const u32*)(hb + (size_t)s1 * 128);
      a0 += bf2f(v0); a1 += bf2f(v0 >> 16);
      b0 += bf2f(v1); b1 += bf2f(v1 >> 16);
    }
    if (j < e){
      u32 i0 = j - jb;
      u32 s0 = (i0 < 64) ? __shfl(pre, (int)i0) : src_s[j];
      u32 v0 = *(const u32*)(hb + (size_t)s0 * 128);
      a0 += bf2f(v0); a1 += bf2f(v0 >> 16);
    }
    a0 += b0; a1 += b1;
    int c = (int)(e - s);
    float sc = 1.0f / (float)max(c, 1);
    u32 m0 = (u32)f2bf(a0 * sc), m1 = (u32)f2bf(a1 * sc);
    ou[r >> 1]       |= m0 << ((r & 1) * 16);
    ou[4 + (r >> 1)] |= m1 << ((r & 1) * 16);
  }
  uint4* dst = (uint4*)(agg + (size_t)d * 1024 + lane * 16);
  dst[0] = make_uint4(ou[0], ou[1], ou[2], ou[3]);
  dst[1] = make_uint4(ou[4], ou[5], ou[6], ou[7]);
}

// ---------------- big GEMM: out[N,128] = [agg | h] (K=1152) @ wcatT + bias
// Split-N=4 with XCD-aware grouping: grid 3136 (98x32); mt=(g>>5)*8+(g&7),
// nq=(g>>3)&3. The 4 n-quarters of a tile are bids g,g+8,g+16,g+24 -> same XCD
// -> A re-reads are L2 hits (R12-verified mechanism). LDS 12 KB, 8 blocks/CU cap.
__global__ __launch_bounds__(256) void k_gemm_big(const u16* __restrict__ h,
                                                  const u16* __restrict__ agg,
                                                  const u16* __restrict__ wT,
                                                  const void* __restrict__ bias,
                                                  float* __restrict__ out, const u32* md,
                                                  float* __restrict__ stats, int do_stats){
  __shared__ u16 As[64][64];    // LDS slot (row, c8) holds global (row, c8^(row&7))
  __shared__ u16 Bs[32][64];
  u32 fm = md[0];
  int g = blockIdx.x;
  int mt = (g >> 5) * 8 + (g & 7);  // m-tile id; quarters share mt's XCD (mod 8)
  int nq = (g >> 3) & 3;            // this block's 32-col output quarter
  int m0 = mt * 64;
  int tid = threadIdx.x;
  int w = tid >> 6, lane = tid & 63, qd = lane >> 4, l16 = lane & 15;

  int rin = lane >> 3;              // row within 8-row chunk
  int sc8 = (lane & 7) ^ rin;       // pre-swizzled source col8 (involution)

  // A: 2 chunks/wave (8 rows x 64 cols = 1 KB each); B: 1 chunk/wave
  const u16* agA[2]; const u16* hA[2]; u16* ldsA[2];
  #pragma unroll
  for (int i = 0; i < 2; i++){
    int row = (w * 2 + i) * 8 + rin;
    int node = m0 + row; if (node > NN - 1) node = NN - 1;
    agA[i] = agg + (size_t)node * 1024 + sc8 * 8;
    hA[i]  = h + (size_t)node * 128 + sc8 * 8;
    ldsA[i] = &As[(w * 2 + i) * 8][0];      // wave-uniform chunk base
  }
  const u16* wB = wT + (size_t)(nq * 32 + w * 8 + rin) * 1152 + sc8 * 8;
  u16* ldsB = &Bs[w * 8][0];

  f32x4 acc[2];
  acc[0] = (f32x4){0.f,0.f,0.f,0.f};
  acc[1] = (f32x4){0.f,0.f,0.f,0.f};

  int sw = (l16 & 7) << 3;   // read-side XOR in elems
  for (int k0 = 0; k0 < 1152; k0 += 64){
    __syncthreads();                       // prev MFMA reads done; LDS free
    if (k0 < 1024){
      gl_lds16(agA[0] + k0, ldsA[0]);
      gl_lds16(agA[1] + k0, ldsA[1]);
    } else {
      gl_lds16(hA[0] + (k0 - 1024), ldsA[0]);
      gl_lds16(hA[1] + (k0 - 1024), ldsA[1]);
    }
    gl_lds16(wB + k0, ldsB);
    __syncthreads();                       // vmcnt(0) drain -> tile ready
    #pragma unroll
    for (int kk = 0; kk < 64; kk += 32){
      bf16x8 a = *(const bf16x8*)(&As[w * 16 + l16][(kk + qd * 8) ^ sw]);
      #pragma unroll
      for (int ct = 0; ct < 2; ct++){
        bf16x8 b = *(const bf16x8*)(&Bs[ct * 16 + l16][(kk + qd * 8) ^ sw]);
        acc[ct] = __builtin_amdgcn_mfma_f32_16x16x32_bf16(a, b, acc[ct], 0, 0, 0);
      }
    }
  }

  float sarr[2], s2arr[2];
  #pragma unroll
  for (int ct = 0; ct < 2; ct++){
    int col = nq * 32 + ct * 16 + l16;
    float bv = ldf(bias, col, fm);
    float s = 0.f, s2 = 0.f;
    int rbase = m0 + w * 16 + qd * 4;
    #pragma unroll
    for (int rg = 0; rg < 4; rg++){
      int node = rbase + rg;
      if (node < NN){
        float v = acc[ct][rg] + bv;
        out[(size_t)node * 128 + col] = v;
        s += v; s2 += v * v;
      }
    }
    s  += __shfl_xor(s, 16);  s  += __shfl_xor(s, 32);
    s2 += __shfl_xor(s2, 16); s2 += __shfl_xor(s2, 32);
    sarr[ct] = s; s2arr[ct] = s2;
  }
  if (do_stats){
    float* red = (float*)&As[0][0];        // 256 floats = 1 KB (As is 8 KB)
    __syncthreads();                       // all MFMA reads of As done
    if (qd == 0){
      #pragma unroll
      for (int ct = 0; ct < 2; ct++){
        red[w * 64 + ct * 16 + l16] = sarr[ct];
        red[w * 64 + 32 + ct * 16 + l16] = s2arr[ct];
      }
    }
    __syncthreads();
    if (tid < 64){
      float v = red[tid] + red[64 + tid] + red[128 + tid] + red[192 + tid];
      int which = tid >> 5, colq = tid & 31;
      unsafeAtomicAdd(&stats[which * 128 + nq * 32 + colq], v);
    }
  }
}

__global__ void k_bnapply(const float* __restrict__ out, const float* __restrict__ stats,
                          const void* __restrict__ g, const void* __restrict__ beta,
                          u16* __restrict__ hout, const u32* md, u32* flags, u32 layerbit){
  u32 fm = md[0];
  int idx = (blockIdx.x * 256 + threadIdx.x) * 4;
  if (idx >= NN * 128) return;
  int col = idx & 127;
  float4 v = *(const float4*)(out + idx);
  float vv[4] = {v.x, v.y, v.z, v.w};
  bool bad = false;
  u16 o[4];
  for (int j = 0; j < 4; j++){
    int c = col + j;
    float mu = stats[c] * (1.0f / NN);
    float var = fmaxf(stats[128 + c] * (1.0f / NN) - mu * mu, 0.f);
    float sc = ldf(g, c, fm) * rsqrtf(var + 1e-5f);
    float sh = ldf(beta, c, fm) - mu * sc;
    float r = vv[j] * sc + sh;
    if (r != r || sc != sc){ bad = true; r = 0.f; }
    o[j] = f2bf(lrelu(r));
  }
  unsigned long long bal = __ballot(bad);
  if (bal && (threadIdx.x & 63) == 0) atomicOr(flags, layerbit);
  uint2 st;
  st.x = (u32)o[0] | ((u32)o[1] << 16);
  st.y = (u32)o[2] | ((u32)o[3] << 16);
  *(uint2*)(hout + idx) = st;
}

// ---------------- attention scores via MFMA: no LDS, A-frags direct from global,
// fused per-block score max (atomicMax into smax). BM=64, 782 blocks.
__global__ __launch_bounds__(256) void k_scores_mfma(const float* __restrict__ emb,
                                                     const u16* __restrict__ wext,
                                                     float* __restrict__ scores, u32* smax){
  int m0 = blockIdx.x * 64;
  int tid = threadIdx.x;
  int w = tid >> 6, lane = tid & 63, qd = lane >> 4, l16 = lane & 15;
  int na = m0 + w * 16 + l16; if (na > NN - 1) na = NN - 1;
  const float* arow = emb + (size_t)na * 128;
  f32x4 acc[4];
  #pragma unroll
  for (int j = 0; j < 4; j++) acc[j] = (f32x4){0.f,0.f,0.f,0.f};
  #pragma unroll
  for (int k0 = 0; k0 < 4; k0++){
    float4 f0 = *(const float4*)(arow + k0 * 32 + qd * 8);
    float4 f1 = *(const float4*)(arow + k0 * 32 + qd * 8 + 4);
    bf16x8 a = cvt8(f0, f1);
    #pragma unroll
    for (int ct = 0; ct < 4; ct++){
      bf16x8 b = *(const bf16x8*)(wext + WX_A1T + (size_t)(ct * 16 + l16) * 128 + k0 * 32 + qd * 8);
      acc[ct] = __builtin_amdgcn_mfma_f32_16x16x32_bf16(a, b, acc[ct], 0, 0, 0);
    }
  }
  float a1v[4], a2v[4];
  #pragma unroll
  for (int ct = 0; ct < 4; ct++){
    a1v[ct] = bf2f(wext[WX_a1 + ct * 16 + l16]);
    a2v[ct] = bf2f(wext[WX_A2 + ct * 16 + l16]);
  }
  float a2s = bf2f(wext[WX_a2s]);
  float bm = -1e30f;
  #pragma unroll
  for (int rg = 0; rg < 4; rg++){
    float s = 0.f;
    #pragma unroll
    for (int ct = 0; ct < 4; ct++)
      s += lrelu(acc[ct][rg] + a1v[ct]) * a2v[ct];
    s += __shfl_xor(s, 1); s += __shfl_xor(s, 2);
    s += __shfl_xor(s, 4); s += __shfl_xor(s, 8);
    int row = m0 + w * 16 + qd * 4 + rg;
    float sf = s + a2s;
    if (row < NN){
      bm = fmaxf(bm, sf);
      if (l16 == 0) scores[row] = sf;
    }
  }
  bm = fmaxf(bm, __shfl_xor(bm, 16));
  bm = fmaxf(bm, __shfl_xor(bm, 32));
  if (lane == 0) atomicMax(smax, (bm >= -1e29f) ?
      ((__float_as_uint(bm) & 0x80000000u) ? ~__float_as_uint(bm) : (__float_as_uint(bm) | 0x80000000u)) : 0u);
}

__device__ __forceinline__ float funmap(u32 m){
  union{u32 u; float f;} x;
  x.u = (m & 0x80000000u) ? (m ^ 0x80000000u) : ~m;
  return x.f;
}

__global__ void k_expsum(const float* __restrict__ scores, const u32* smax,
                         float* __restrict__ attnw, float* ssum, u32* flags){
  float mx = funmap(*smax);
  int gid = blockIdx.x * 256 + threadIdx.x;
  if (mx != mx){ if (gid == 0) atomicOr(flags, 32u); mx = 0.f; }
  float s = 0.f;
  bool bad = false;
  for (int i = gid; i < NN; i += 256 * 128){
    float e = __expf(scores[i] - mx);
    if (e != e){ bad = true; e = 0.f; }
    attnw[i] = e; s += e;
  }
  unsigned long long bal = __ballot(bad);
  if (bal && (threadIdx.x & 63) == 0) atomicOr(flags, 32u);
  for (int off = 32; off; off >>= 1) s += __shfl_down(s, off);
  if ((threadIdx.x & 63) == 0) unsafeAtomicAdd(ssum, s);
}

// ---------------- pooling: 32 nodes/block, per-run atomics (1563 blocks)
constexpr int POOL_CHUNK = 32;
__global__ __launch_bounds__(128) void k_pool(const float* __restrict__ emb,
                                              const float* __restrict__ attnw,
                                              const float* __restrict__ ssum,
                                              const int* __restrict__ batch,
                                              float* __restrict__ gemb, u32* flags){
  int t = threadIdx.x;
  int n0 = blockIdx.x * POOL_CHUNK;
  if (n0 >= NN) return;
  int n1 = min(n0 + POOL_CHUNK, NN);
  float sv = *ssum;
  bool bad = !(sv > 0.f) || (sv != sv);
  if (bad && t == 0 && blockIdx.x == 0) atomicOr(flags, 64u);
  float rs = bad ? 0.f : 1.0f / sv;
  int cur = batch[n0];
  float acc = 0.f;
  for (int n = n0; n < n1; n++){
    int b = batch[n];
    if (b != cur){ unsafeAtomicAdd(&gemb[cur * 128 + t], acc * rs); acc = 0.f; cur = b; }
    acc += emb[(size_t)n * 128 + t] * attnw[n];
  }
  unsafeAtomicAdd(&gemb[cur * 128 + t], acc * rs);
}

// ---------------- gembC[g][n] = gemb[g] . C1T_hi[n] + c1[n]  (64 x 128, K=128, f32)
__global__ void k_gembC(const float* __restrict__ gemb, const u16* __restrict__ wext,
                        float* __restrict__ gembC){
  int idx = blockIdx.x * 256 + threadIdx.x;
  if (idx >= 64 * 128) return;
  int g = idx >> 7, n = idx & 127;
  const float* gr = gemb + g * 128;
  const u16* wr = wext + WX_C1T + (size_t)n * 256 + 128;
  float s = 0.f;
  #pragma unroll 8
  for (int k = 0; k < 128; k++) s += gr[k] * bf2f(wr[k]);
  gembC[idx] = s + bf2f(wext[WX_c1 + n]);
}

// ---------------- final combiner: phase1 = emb @ C1_lo (A-frags direct from global)
// + gembC[batch] gather; Hs LDS relay; phase2 = Hs @ C2T; row L2 normalize.
__global__ __launch_bounds__(256) void k_final_mfma(const float* __restrict__ emb,
                                                    const float* __restrict__ gembC,
                                                    const int* __restrict__ batch,
                                                    const u16* __restrict__ wext,
                                                    void* __restrict__ outp,
                                                    const u32* md){
  __shared__ u16 Hs[64][136];   // 17.4 KB
  u32 fm = md[0];
  int m0 = blockIdx.x * 64;
  int tid = threadIdx.x;
  int w = tid >> 6, lane = tid & 63, qd = lane >> 4, l16 = lane & 15;
  int na = m0 + w * 16 + l16; if (na > NN - 1) na = NN - 1;
  const float* arow = emb + (size_t)na * 128;

  f32x4 acc[8];
  #pragma unroll
  for (int j = 0; j < 8; j++) acc[j] = (f32x4){0.f,0.f,0.f,0.f};
  #pragma unroll
  for (int k0 = 0; k0 < 4; k0++){
    float4 f0 = *(const float4*)(arow + k0 * 32 + qd * 8);
    float4 f1 = *(const float4*)(arow + k0 * 32 + qd * 8 + 4);
    bf16x8 a = cvt8(f0, f1);
    #pragma unroll
    for (int ct = 0; ct < 8; ct++){
      bf16x8 b = *(const bf16x8*)(wext + WX_C1T + (size_t)(ct * 16 + l16) * 256 + k0 * 32 + qd * 8);
      acc[ct] = __builtin_amdgcn_mfma_f32_16x16x32_bf16(a, b, acc[ct], 0, 0, 0);
    }
  }
  // epilogue 1: + gembC[batch[row]][col] (c1 folded in), lrelu, -> Hs
  int rbase = w * 16 + qd * 4;
  int gg[4];
  #pragma unroll
  for (int rg = 0; rg < 4; rg++){
    int node = m0 + rbase + rg; if (node > NN - 1) node = NN - 1;
    gg[rg] = batch[node];
  }
  #pragma unroll
  for (int ct = 0; ct < 8; ct++){
    int col = ct * 16 + l16;
    #pragma unroll
    for (int rg = 0; rg < 4; rg++){
      float h = acc[ct][rg] + gembC[gg[rg] * 128 + col];
      Hs[rbase + rg][col] = f2bf(lrelu(h));
    }
  }
  __syncthreads();
  f32x4 acc2[8];
  #pragma unroll
  for (int j = 0; j < 8; j++) acc2[j] = (f32x4){0.f,0.f,0.f,0.f};
  #pragma unroll
  for (int k0 = 0; k0 < 4; k0++){
    bf16x8 a = *(const bf16x8*)(&Hs[w * 16 + l16][k0 * 32 + qd * 8]);
    #pragma unroll
    for (int ct = 0; ct < 8; ct++){
      bf16x8 b = *(const bf16x8*)(wext + WX_C2T + (size_t)(ct * 16 + l16) * 128 + k0 * 32 + qd * 8);
      acc2[ct] = __builtin_amdgcn_mfma_f32_16x16x32_bf16(a, b, acc2[ct], 0, 0, 0);
    }
  }
  float c2v[8];
  #pragma unroll
  for (int ct = 0; ct < 8; ct++) c2v[ct] = bf2f(wext[WX_c2 + ct * 16 + l16]);
  #pragma unroll
  for (int rg = 0; rg < 4; rg++){
    float ss = 0.f;
    #pragma unroll
    for (int ct = 0; ct < 8; ct++){
      float o = acc2[ct][rg] + c2v[ct];
      ss += o * o;
    }
    ss += __shfl_xor(ss, 1); ss += __shfl_xor(ss, 2);
    ss += __shfl_xor(ss, 4); ss += __shfl_xor(ss, 8);
    float sc = 1.0f / fmaxf(sqrtf(ss), 1e-12f);
    int row = m0 + rbase + rg;
    if (row < NN){
      if (fm){
        float* op = (float*)outp;
        #pragma unroll
        for (int ct = 0; ct < 8; ct++)
          op[(size_t)row * 128 + ct * 16 + l16] = (acc2[ct][rg] + c2v[ct]) * sc;
      } else {
        u16* op = (u16*)outp;
        #pragma unroll
        for (int ct = 0; ct < 8; ct++)
          op[(size_t)row * 128 + ct * 16 + l16] = f2bf((acc2[ct][rg] + c2v[ct]) * sc);
      }
    }
  }
}

// ---------------- diag sentinels
__global__ void k_diag(const u32* pairStart, const u32* flags, const u32* md, void* outp){
  if (threadIdx.x != 0 || blockIdx.x != 0) return;
  u32 fm = md[0];
  u32 f = flags[0];
  if (pairStart[NKEY] != (u32)EE) f |= 1u;
  for (int b = 0; b < 9; b++){
    if (f & (1u << b)){
      float s = (float)(131072 >> b);
      if (fm) ((float*)outp)[b] = s;
      else ((u16*)outp)[b] = f2bf(s);
    }
  }
}
__global__ void k_wsfail(u32* outp){ outp[0] = 0x43000000u; }

// ---------------- workspace layout (bytes)
constexpr size_t O_OUT   = 0;          // f32 N*128; pre-GEMM aliases: cursor/blockSum/blockBase
constexpr size_t O_H     = 25600000;
constexpr size_t O_XBF   = 38400000;
constexpr size_t O_WCAT  = 51200000;
constexpr size_t O_WEXT  = 52084736;
constexpr size_t O_EI    = 52200448;
constexpr size_t O_ET    = 56200448;
constexpr size_t O_BAT   = 58200448;
constexpr size_t O_SRC   = 58400448;   // 2 MB (src_s)
constexpr size_t O_PST   = 60400448;   // pairStart: (NKEY+1) u32 = 1,600,004 B; gembC in tail slack
constexpr size_t O_GEMBC = 62100448;   // 32 KB (inside O_PST..O_CNT slack)
constexpr size_t O_CNT   = 62400448;   // 1.6 MB
constexpr size_t O_SCO   = 65600448;
constexpr size_t O_AW    = 65800448;
constexpr size_t O_GEMB  = 66000448;
constexpr size_t O_STATS = 66033216;
constexpr size_t O_MISC  = 66035264;
constexpr size_t O_AGG   = 66035520;   // bf16 N*1024 = 102,400,000
constexpr size_t WS_NEED = 168435520;

extern "C" void kernel_launch(void* const* d_in, const int* in_sizes, int n_in,
                              void* d_out, int out_size, void* d_ws, size_t ws_size,
                              hipStream_t stream) {
  const void* x     = d_in[0];
  const void* ei    = d_in[1];
  const void* et    = d_in[2];
  const void* batch = d_in[3];
  const void* W1 = d_in[4],  *r1 = d_in[5],  *b1 = d_in[6];
  const void* W2 = d_in[7],  *r2 = d_in[8],  *b2 = d_in[9];
  const void* W3 = d_in[10], *r3 = d_in[11], *b3 = d_in[12];
  const void* g1 = d_in[13], *be1 = d_in[14];
  const void* g2 = d_in[15], *be2 = d_in[16];
  const void* A1 = d_in[17], *a1 = d_in[18];
  const void* A2 = d_in[19], *a2 = d_in[20];
  const void* C1 = d_in[21], *c1 = d_in[22];
  const void* C2 = d_in[23], *c2 = d_in[24];

  if (ws_size < WS_NEED){ k_wsfail<<<1, 1, 0, stream>>>((u32*)d_out); return; }
  char* ws = (char*)d_ws;
  float* out   = (float*)(ws + O_OUT);
  u16*   hbuf  = (u16*)(ws + O_H);
  u16*   xbf   = (u16*)(ws + O_XBF);
  u16*   wcat  = (u16*)(ws + O_WCAT);
  u16*   wext  = (u16*)(ws + O_WEXT);
  int*   ei_c  = (int*)(ws + O_EI);
  int*   et_c  = (int*)(ws + O_ET);
  int*   bat_c = (int*)(ws + O_BAT);
  u32*   src_s = (u32*)(ws + O_SRC);
  u32*   pairStart = (u32*)(ws + O_PST);
  float* gembC = (float*)(ws + O_GEMBC);
  u32*   cnt   = (u32*)(ws + O_CNT);
  float* sco   = (float*)(ws + O_SCO);
  float* aw    = (float*)(ws + O_AW);
  float* gemb  = (float*)(ws + O_GEMB);
  float* stats = (float*)(ws + O_STATS);
  u32*   misc  = (u32*)(ws + O_MISC);
  u16*   aggb  = (u16*)(ws + O_AGG);
  u32* cursor    = (u32*)(ws + O_OUT);
  u32* blockSum  = (u32*)(ws + O_OUT + 1600000);
  u32* blockBase = (u32*)(ws + O_OUT + 1604096);
  u32* smax = misc + 25;
  float* ssum = (float*)(misc + 26);
  u32* flags = misc + 27;
  u32* md = misc + 28;

  hipMemsetAsync(ws + O_CNT, 0, 1600000, stream);
  hipMemsetAsync(ws + O_GEMB, 0, 32768 + 2048 + 256, stream);

  k_fdetect<<<1, 256, 0, stream>>>(x, md);
  k_idetect<<<1, 256, 0, stream>>>(et, md);
  k_icvt<<<6055, 256, 0, stream>>>(ei, et, batch, ei_c, et_c, bat_c, cnt, md);
  k_xcvt<<<6250, 256, 0, stream>>>(x, xbf, md, flags);
  k_wcat<<<1728, 256, 0, stream>>>(W1, r1, W2, r2, W3, r3, wcat, md, flags);
  k_wext<<<227, 256, 0, stream>>>(A1, a1, A2, a2, C1, c1, C2, c2, wext, md);

  k_pairA<<<PAIR_B, 256, 0, stream>>>(cnt, blockSum);
  k_pairB<<<1, 64, 0, stream>>>(blockSum, blockBase);
  k_pairC<<<PAIR_B, 256, 0, stream>>>(cnt, blockBase, pairStart, cursor);
  k_sort3<<<(EE + 255) / 256, 256, 0, stream>>>(ei_c, et_c, pairStart, cursor, src_s);

  const void* bias[3] = {b1, b2, b3};
  const void* gam[2] = {g1, g2};
  const void* bet[2] = {be1, be2};
  const u16* hin = xbf;
  for (int L = 0; L < 3; L++){
    const u16* wT = wcat + (size_t)L * 128 * 1152;
    k_agg<<<(NN + 3) / 4, 256, 0, stream>>>(hin, pairStart, src_s, aggb);
    k_gemm_big<<<3136, 256, 0, stream>>>(hin, aggb, wT, bias[L], out, md,
                                         stats + (L < 2 ? L * 256 : 0), (L < 2) ? 1 : 0);
    if (L < 2){
      k_bnapply<<<6250, 256, 0, stream>>>(out, stats + L * 256, gam[L], bet[L], hbuf, md, flags, 4u << L);
      hin = hbuf;
    }
  }
  k_scores_mfma<<<(NN + 63) / 64, 256, 0, stream>>>(out, wext, sco, smax);
  k_expsum<<<128, 256, 0, stream>>>(sco, smax, aw, ssum, flags);
  k_pool<<<(NN + POOL_CHUNK - 1) / POOL_CHUNK, 128, 0, stream>>>(out, aw, ssum, bat_c, gemb, flags);
  k_gembC<<<32, 256, 0, stream>>>(gemb, wext, gembC);
  k_final_mfma<<<(NN + 63) / 64, 256, 0, stream>>>(out, gembC, bat_c, wext, d_out, md);
  k_diag<<<1, 64, 0, stream>>>(pairStart, flags, md, d_out);
}

// Round 14
// 609.741 us; speedup vs baseline: 1.0369x; 1.0369x over previous
//
#include <hip/hip_runtime.h>
#include <hip/hip_bf16.h>

typedef unsigned int u32;
typedef unsigned short u16;
typedef __bf16 bf16_t;
typedef bf16_t bf16x8 __attribute__((ext_vector_type(8)));
typedef float f32x4 __attribute__((ext_vector_type(4)));

constexpr int NN = 50000;
constexpr int EE = 500000;
constexpr int RR = 8;
constexpr int NKEY = RR * NN;               // 400000
constexpr int PAIR_B = (NKEY + 511) / 512;  // 782

// wext element offsets (bf16 elems)
constexpr int WX_A1T = 0;       // [64][128]
constexpr int WX_C1T = 8192;    // [128][256]
constexpr int WX_C2T = 40960;   // [128][128]
constexpr int WX_A2  = 57344;   // [64]
constexpr int WX_a1  = 57408;   // [64]
constexpr int WX_c1  = 57472;   // [128]
constexpr int WX_c2  = 57600;   // [128]
constexpr int WX_a2s = 57728;   // [1]
constexpr int WX_TOT = 57729;

__device__ __forceinline__ float bf2f(u32 v){
  union { u32 u; float f; } x; x.u = (v & 0xFFFFu) << 16; return x.f;
}
__device__ __forceinline__ u16 f2bf(float f){
  union { u32 u; float f; } x; x.f = f;
  u32 r = x.u + 0x7FFFu + ((x.u >> 16) & 1u);
  return (u16)(r >> 16);
}
__device__ __forceinline__ float lrelu(float x){ return x > 0.f ? x : 0.1f * x; }
__device__ __forceinline__ float ldf(const void* p, int i, u32 fm){
  return fm ? ((const float*)p)[i] : bf2f(((const u16*)p)[i]);
}
// direct global->LDS DMA, 16B per lane; LDS dest is wave-uniform base + lane*16
__device__ __forceinline__ void gl_lds16(const u16* g, u16* l){
  __builtin_amdgcn_global_load_lds((const __attribute__((address_space(1))) u32*)g,
                                   (__attribute__((address_space(3))) u32*)l, 16, 0, 0);
}

// ---------------- dtype detectors (merged) ----------------
__global__ void k_detect(const void* x, const void* et, u32* md){
  __shared__ u32 c;
  if (threadIdx.x == 0) c = 0;
  __syncthreads();
  u32 loc = 0;
  if (blockIdx.x == 0){
    const u16* p = (const u16*)x;
    for (int j = 0; j < 16; j++){
      u16 v = p[threadIdx.x * 16 + j];
      u32 e = (v >> 7) & 0xFF;
      if (e >= 0xFD) loc++;
    }
    atomicAdd(&c, loc);
    __syncthreads();
    if (threadIdx.x == 0) md[0] = (c >= 4) ? 1u : 0u;
  } else {
    const int* p = (const int*)et;
    for (int j = 0; j < 8; j++){
      int idx = 2 * (threadIdx.x * 8 + j) + 1;
      if (p[idx] != 0) loc++;
    }
    atomicAdd(&c, loc);
    __syncthreads();
    if (threadIdx.x == 0) md[1] = (c == 0) ? 1u : 0u;
  }
}

// ---------------- int conversion + x conversion (merged) + fused (dst,rel) count
// blocks [0,6055): int paths; blocks [6055,12305): x->bf16
__global__ void k_cvt(const void* ei, const void* et, const void* bat, const void* x,
                      int* ei_c, int* et_c, int* bat_c, u16* xb,
                      u32* __restrict__ cnt, const u32* md, u32* flags){
  if (blockIdx.x < 6055){
    u32 im = md[1];
    int i = blockIdx.x * 256 + threadIdx.x;
    if (i < EE){
      const int* p = (const int*)ei;
      ei_c[i] = im ? p[2 * i] : p[i];
    } else if (i < 2 * EE){
      int j = i - EE;
      const int* p = (const int*)ei;
      const int* pt = (const int*)et;
      int d = im ? p[2 * i] : p[i];
      int r = im ? pt[2 * j] : pt[j];
      ei_c[i] = d;
      atomicAdd(&cnt[d * RR + r], 1u);
    } else if (i < 3 * EE){
      int j = i - 2 * EE;
      const int* p = (const int*)et;
      et_c[j] = im ? p[2 * j] : p[j];
    } else if (i < 3 * EE + NN){
      int j = i - 3 * EE;
      const int* p = (const int*)bat;
      bat_c[j] = im ? p[2 * j] : p[j];
    }
  } else {
    u32 fm = md[0];
    int i4 = ((blockIdx.x - 6055) * 256 + threadIdx.x) * 4;
    if (i4 >= NN * 128) return;
    float v[4];
    if (fm){
      float4 f = *(const float4*)((const float*)x + i4);
      v[0]=f.x; v[1]=f.y; v[2]=f.z; v[3]=f.w;
    } else {
      uint2 u = *(const uint2*)((const u16*)x + i4);
      v[0]=bf2f(u.x); v[1]=bf2f(u.x>>16); v[2]=bf2f(u.y); v[3]=bf2f(u.y>>16);
    }
    bool bad = false;
    u16 o[4];
    for (int j = 0; j < 4; j++){
      if (v[j] != v[j]){ bad = true; v[j] = 0.f; }
      o[j] = f2bf(v[j]);
    }
    unsigned long long bal = __ballot(bad);
    if (bal && (threadIdx.x & 63) == 0) atomicOr(flags, 2u);
    uint2 st;
    st.x = (u32)o[0] | ((u32)o[1] << 16);
    st.y = (u32)o[2] | ((u32)o[3] << 16);
    *(uint2*)(xb + i4) = st;
  }
}

// ---------------- weight transpose + small-MLP weight prep (merged)
// blocks [0,1728): wcatT[L][n][k'] (k'<1024: k'=c*8+r -> W[L][r*128+c][n]; else root)
// blocks [1728,1955): wext
__global__ void k_wprep(const void* W1, const void* r1, const void* W2, const void* r2,
                        const void* W3, const void* r3,
                        const void* A1, const void* a1, const void* A2, const void* a2,
                        const void* C1, const void* c1, const void* C2, const void* c2,
                        u16* wcatT, u16* wext, const u32* md, u32* flags){
  u32 fm = md[0];
  if (blockIdx.x < 1728){
    int idx = blockIdx.x * 256 + threadIdx.x;
    int L = idx / (128 * 1152);
    int rem = idx % (128 * 1152);
    int n = rem / 1152, k = rem % 1152;
    const void* W  = (L == 0) ? W1 : ((L == 1) ? W2 : W3);
    const void* rt = (L == 0) ? r1 : ((L == 1) ? r2 : r3);
    float v;
    if (k < 1024){
      int r = k & 7, c = k >> 3;
      v = ldf(W, (r * 128 + c) * 128 + n, fm);
    } else {
      v = ldf(rt, (k - 1024) * 128 + n, fm);
    }
    if (v != v){ v = 0.f; atomicOr(flags, 2u); }
    wcatT[idx] = f2bf(v);
  } else {
    int idx = (blockIdx.x - 1728) * 256 + threadIdx.x;
    if (idx >= WX_TOT) return;
    float v;
    if (idx < WX_C1T){
      int n = idx >> 7, k = idx & 127;
      v = ldf(A1, k * 64 + n, fm);
    } else if (idx < WX_C2T){
      int j = idx - WX_C1T; int n = j >> 8, k = j & 255;
      v = ldf(C1, k * 128 + n, fm);
    } else if (idx < WX_A2){
      int j = idx - WX_C2T; int n = j >> 7, k = j & 127;
      v = ldf(C2, k * 128 + n, fm);
    } else if (idx < WX_a1){ v = ldf(A2, idx - WX_A2, fm); }
    else if (idx < WX_c1){ v = ldf(a1, idx - WX_a1, fm); }
    else if (idx < WX_c2){ v = ldf(c1, idx - WX_c1, fm); }
    else if (idx < WX_a2s){ v = ldf(c2, idx - WX_c2, fm); }
    else { v = ldf(a2, 0, fm); }
    wext[idx] = f2bf(v);
  }
}

// ---------------- (dst,rel) counting sort: key = d*RR + r (dst-major) ----------------
__global__ void k_pairA(const u32* __restrict__ cnt, u32* __restrict__ blockSum){
  __shared__ u32 sd[256];
  int b = blockIdx.x, t = threadIdx.x;
  u32 s = 0;
  for (int j = 0; j < 2; j++){
    int key = b * 512 + t * 2 + j;
    if (key < NKEY) s += cnt[key];
  }
  sd[t] = s; __syncthreads();
  for (int off = 128; off; off >>= 1){ if (t < off) sd[t] += sd[t + off]; __syncthreads(); }
  if (t == 0) blockSum[b] = sd[0];
}
__global__ void k_pairB(const u32* __restrict__ blockSum, u32* __restrict__ blockBase){
  int lane = threadIdx.x;   // 64
  u32 loc[13]; u32 s = 0;
  for (int j = 0; j < 13; j++){
    int b = lane * 13 + j;
    u32 v = (b < PAIR_B) ? blockSum[b] : 0u;
    loc[j] = s; s += v;
  }
  u32 tot = s;
  for (int off = 1; off < 64; off <<= 1){
    u32 x = __shfl_up(tot, off);
    if (lane >= off) tot += x;
  }
  u32 excl = tot - s;
  for (int j = 0; j < 13; j++){
    int b = lane * 13 + j;
    if (b < PAIR_B) blockBase[b] = excl + loc[j];
  }
}
__global__ void k_pairC(const u32* __restrict__ cnt, const u32* __restrict__ blockBase,
                        u32* __restrict__ pairStart, u32* __restrict__ cursor){
  __shared__ u32 sd[256];
  int b = blockIdx.x, t = threadIdx.x;
  int k0 = b * 512 + t * 2;
  u32 v0 = 0, v1 = 0;
  if (k0 < NKEY) v0 = cnt[k0];
  if (k0 + 1 < NKEY) v1 = cnt[k0 + 1];
  sd[t] = v0 + v1; __syncthreads();
  for (int off = 1; off < 256; off <<= 1){
    u32 x = (t >= off) ? sd[t - off] : 0u;
    __syncthreads();
    sd[t] += x;
    __syncthreads();
  }
  u32 excl = sd[t] - (v0 + v1);
  u32 base = blockBase[b] + excl;
  if (k0 < NKEY){ pairStart[k0] = base; cursor[k0] = 0u; }
  if (k0 + 1 < NKEY){ pairStart[k0 + 1] = base + v0; cursor[k0 + 1] = 0u; }
  if (k0 + 1 == NKEY - 1) pairStart[NKEY] = base + v0 + v1;   // genuine scan total
}
__global__ void k_sort3(const int* __restrict__ ei, const int* __restrict__ et,
                        const u32* __restrict__ pairStart, u32* __restrict__ cursor,
                        u32* __restrict__ src_s){
  int e = blockIdx.x * 256 + threadIdx.x;
  if (e >= EE) return;
  int r = et[e], d = ei[EE + e];
  u32 key = (u32)d * RR + (u32)r;
  u32 p = pairStart[key] + atomicAdd(&cursor[key], 1u);
  src_s[p] = (u32)ei[e];
}

// ---------------- aggregation: one wave per dst node, all 8 relations
// agg layout: [d][c][r] (elem = c*8+r). Preloaded src broadcast + unroll-2 gather;
// per-lane 2 cols x 8 rel -> one 32B contiguous store (2KB/node coalesced).
__global__ __launch_bounds__(256) void k_agg(const u16* __restrict__ h,
                                             const u32* __restrict__ pairStart,
                                             const u32* __restrict__ src_s,
                                             u16* __restrict__ agg){
  int d = blockIdx.x * 4 + (threadIdx.x >> 6);
  if (d >= NN) return;
  int lane = threadIdx.x & 63;
  const uint4* p4 = (const uint4*)(pairStart + d * 8);
  uint4 q0 = p4[0], q1 = p4[1];
  u32 ps[9];
  ps[0]=q0.x; ps[1]=q0.y; ps[2]=q0.z; ps[3]=q0.w;
  ps[4]=q1.x; ps[5]=q1.y; ps[6]=q1.z; ps[7]=q1.w;
  ps[8]=pairStart[d * 8 + 8];
  u32 jb = ps[0], je = ps[8];
  // coalesced preload of up to 64 src indices for the whole node
  u32 pre = 0;
  if (jb + lane < je) pre = src_s[jb + lane];
  const u16* hb = h + lane * 2;
  u32 ou[8] = {0,0,0,0,0,0,0,0};
  #pragma unroll
  for (int r = 0; r < 8; r++){
    u32 s = ps[r], e = ps[r + 1];
    float a0 = 0.f, a1 = 0.f, b0 = 0.f, b1 = 0.f;
    u32 j = s;
    for (; j + 1 < e; j += 2){
      u32 i0 = j - jb;
      u32 s0 = (i0 < 64) ? __shfl(pre, (int)i0) : src_s[j];
      u32 s1 = (i0 + 1 < 64) ? __shfl(pre, (int)(i0 + 1)) : src_s[j + 1];
      u32 v0 = *(const u32*)(hb + (size_t)s0 * 128);
      u32 v1 = *(const u32*)(hb + (size_t)s1 * 128);
      a0 += bf2f(v0); a1 += bf2f(v0 >> 16);
      b0 += bf2f(v1); b1 += bf2f(v1 >> 16);
    }
    if (j < e){
      u32 i0 = j - jb;
      u32 s0 = (i0 < 64) ? __shfl(pre, (int)i0) : src_s[j];
      u32 v0 = *(const u32*)(hb + (size_t)s0 * 128);
      a0 += bf2f(v0); a1 += bf2f(v0 >> 16);
    }
    a0 += b0; a1 += b1;
    int c = (int)(e - s);
    float sc = 1.0f / (float)max(c, 1);
    u32 m0 = (u32)f2bf(a0 * sc), m1 = (u32)f2bf(a1 * sc);
    ou[r >> 1]       |= m0 << ((r & 1) * 16);
    ou[4 + (r >> 1)] |= m1 << ((r & 1) * 16);
  }
  uint4* dst = (uint4*)(agg + (size_t)d * 1024 + lane * 16);
  dst[0] = make_uint4(ou[0], ou[1], ou[2], ou[3]);
  dst[1] = make_uint4(ou[4], ou[5], ou[6], ou[7]);
}

// ---------------- big GEMM: out[N,128] = [agg | h] (K=1152) @ wcatT + bias
// Split-N with XCD-aware pairing: grid 1568 (98x16); mt=(g>>4)*8+(g&7), nh=(g>>3)&1.
// The two n-halves of a tile are bids g and g+8 -> same XCD (mod 8) -> second
// A-read is an L2 hit (R12-verified). Plain stores; fused BN stats; optional bf16
// emb copy for downstream MFMA consumers (bit-identical to their own f2bf).
__global__ __launch_bounds__(256) void k_gemm_big(const u16* __restrict__ h,
                                                  const u16* __restrict__ agg,
                                                  const u16* __restrict__ wT,
                                                  const void* __restrict__ bias,
                                                  float* __restrict__ out, const u32* md,
                                                  float* __restrict__ stats, int do_stats,
                                                  u16* __restrict__ embb){
  __shared__ u16 As[64][64];    // LDS slot (row, c8) holds global (row, c8^(row&7))
  __shared__ u16 Bs[64][64];
  u32 fm = md[0];
  int g = blockIdx.x;
  int mt = (g >> 4) * 8 + (g & 7);  // m-tile id; bids g and g+8 share mt and XCD
  int nh = (g >> 3) & 1;            // this block's 64-col output half
  int m0 = mt * 64;
  int tid = threadIdx.x;
  int w = tid >> 6, lane = tid & 63, qd = lane >> 4, l16 = lane & 15;

  int rin = lane >> 3;              // row within 8-row chunk
  int sc8 = (lane & 7) ^ rin;       // pre-swizzled source col8 (involution)

  // A: 2 chunks/wave (8 rows x 64 cols = 1 KB each); B: 2 chunks/wave
  const u16* agA[2]; const u16* hA[2]; u16* ldsA[2];
  #pragma unroll
  for (int i = 0; i < 2; i++){
    int row = (w * 2 + i) * 8 + rin;
    int node = m0 + row; if (node > NN - 1) node = NN - 1;
    agA[i] = agg + (size_t)node * 1024 + sc8 * 8;
    hA[i]  = h + (size_t)node * 128 + sc8 * 8;
    ldsA[i] = &As[(w * 2 + i) * 8][0];      // wave-uniform chunk base
  }
  const u16* wB[2]; u16* ldsB[2];
  #pragma unroll
  for (int i = 0; i < 2; i++){
    int row = (w * 2 + i) * 8 + rin;        // n-col within half
    wB[i] = wT + (size_t)(nh * 64 + row) * 1152 + sc8 * 8;
    ldsB[i] = &Bs[(w * 2 + i) * 8][0];
  }

  f32x4 acc[4];
  #pragma unroll
  for (int j = 0; j < 4; j++) acc[j] = (f32x4){0.f,0.f,0.f,0.f};

  int sw = (l16 & 7) << 3;   // read-side XOR in elems
  for (int k0 = 0; k0 < 1152; k0 += 64){
    __syncthreads();                       // prev MFMA reads done; LDS free
    if (k0 < 1024){
      gl_lds16(agA[0] + k0, ldsA[0]);
      gl_lds16(agA[1] + k0, ldsA[1]);
    } else {
      gl_lds16(hA[0] + (k0 - 1024), ldsA[0]);
      gl_lds16(hA[1] + (k0 - 1024), ldsA[1]);
    }
    gl_lds16(wB[0] + k0, ldsB[0]);
    gl_lds16(wB[1] + k0, ldsB[1]);
    __syncthreads();                       // vmcnt(0) drain -> tile ready
    #pragma unroll
    for (int kk = 0; kk < 64; kk += 32){
      bf16x8 a = *(const bf16x8*)(&As[w * 16 + l16][(kk + qd * 8) ^ sw]);
      #pragma unroll
      for (int ct = 0; ct < 2; ct++){
        bf16x8 b = *(const bf16x8*)(&Bs[ct * 16 + l16][(kk + qd * 8) ^ sw]);
        acc[ct] = __builtin_amdgcn_mfma_f32_16x16x32_bf16(a, b, acc[ct], 0, 0, 0);
      }
      #pragma unroll
      for (int ct = 2; ct < 4; ct++){
        bf16x8 b = *(const bf16x8*)(&Bs[ct * 16 + l16][(kk + qd * 8) ^ sw]);
        acc[ct] = __builtin_amdgcn_mfma_f32_16x16x32_bf16(a, b, acc[ct], 0, 0, 0);
      }
    }
  }

  float sarr[4], s2arr[4];
  #pragma unroll
  for (int ct = 0; ct < 4; ct++){
    int col = nh * 64 + ct * 16 + l16;
    float bv = ldf(bias, col, fm);
    float s = 0.f, s2 = 0.f;
    int rbase = m0 + w * 16 + qd * 4;
    #pragma unroll
    for (int rg = 0; rg < 4; rg++){
      int node = rbase + rg;
      if (node < NN){
        float v = acc[ct][rg] + bv;
        out[(size_t)node * 128 + col] = v;
        if (embb) embb[(size_t)node * 128 + col] = f2bf(v);
        s += v; s2 += v * v;
      }
    }
    s  += __shfl_xor(s, 16);  s  += __shfl_xor(s, 32);
    s2 += __shfl_xor(s2, 16); s2 += __shfl_xor(s2, 32);
    sarr[ct] = s; s2arr[ct] = s2;
  }
  if (do_stats){
    float* red = (float*)&As[0][0];        // 512 floats = 2 KB (As is 8 KB)
    __syncthreads();                       // all MFMA reads of As done
    if (qd == 0){
      #pragma unroll
      for (int ct = 0; ct < 4; ct++){
        red[w * 128 + ct * 16 + l16] = sarr[ct];
        red[w * 128 + 64 + ct * 16 + l16] = s2arr[ct];
      }
    }
    __syncthreads();
    if (tid < 128){
      float v = red[tid] + red[128 + tid] + red[256 + tid] + red[384 + tid];
      int which = tid >> 6, colh = tid & 63;
      unsafeAtomicAdd(&stats[which * 128 + nh * 64 + colh], v);
    }
  }
}

__global__ void k_bnapply(const float* __restrict__ out, const float* __restrict__ stats,
                          const void* __restrict__ g, const void* __restrict__ beta,
                          u16* __restrict__ hout, const u32* md, u32* flags, u32 layerbit){
  u32 fm = md[0];
  int idx = (blockIdx.x * 256 + threadIdx.x) * 4;
  if (idx >= NN * 128) return;
  int col = idx & 127;
  float4 v = *(const float4*)(out + idx);
  float vv[4] = {v.x, v.y, v.z, v.w};
  bool bad = false;
  u16 o[4];
  for (int j = 0; j < 4; j++){
    int c = col + j;
    float mu = stats[c] * (1.0f / NN);
    float var = fmaxf(stats[128 + c] * (1.0f / NN) - mu * mu, 0.f);
    float sc = ldf(g, c, fm) * rsqrtf(var + 1e-5f);
    float sh = ldf(beta, c, fm) - mu * sc;
    float r = vv[j] * sc + sh;
    if (r != r || sc != sc){ bad = true; r = 0.f; }
    o[j] = f2bf(lrelu(r));
  }
  unsigned long long bal = __ballot(bad);
  if (bal && (threadIdx.x & 63) == 0) atomicOr(flags, layerbit);
  uint2 st;
  st.x = (u32)o[0] | ((u32)o[1] << 16);
  st.y = (u32)o[2] | ((u32)o[3] << 16);
  *(uint2*)(hout + idx) = st;
}

// ---------------- attention scores via MFMA: no LDS, A-frags direct from bf16 emb,
// fused per-block score max (atomicMax into smax). BM=64, 782 blocks.
__global__ __launch_bounds__(256) void k_scores_mfma(const u16* __restrict__ embb,
                                                     const u16* __restrict__ wext,
                                                     float* __restrict__ scores, u32* smax){
  int m0 = blockIdx.x * 64;
  int tid = threadIdx.x;
  int w = tid >> 6, lane = tid & 63, qd = lane >> 4, l16 = lane & 15;
  int na = m0 + w * 16 + l16; if (na > NN - 1) na = NN - 1;
  const u16* arow = embb + (size_t)na * 128;
  f32x4 acc[4];
  #pragma unroll
  for (int j = 0; j < 4; j++) acc[j] = (f32x4){0.f,0.f,0.f,0.f};
  #pragma unroll
  for (int k0 = 0; k0 < 4; k0++){
    bf16x8 a = *(const bf16x8*)(arow + k0 * 32 + qd * 8);
    #pragma unroll
    for (int ct = 0; ct < 4; ct++){
      bf16x8 b = *(const bf16x8*)(wext + WX_A1T + (size_t)(ct * 16 + l16) * 128 + k0 * 32 + qd * 8);
      acc[ct] = __builtin_amdgcn_mfma_f32_16x16x32_bf16(a, b, acc[ct], 0, 0, 0);
    }
  }
  float a1v[4], a2v[4];
  #pragma unroll
  for (int ct = 0; ct < 4; ct++){
    a1v[ct] = bf2f(wext[WX_a1 + ct * 16 + l16]);
    a2v[ct] = bf2f(wext[WX_A2 + ct * 16 + l16]);
  }
  float a2s = bf2f(wext[WX_a2s]);
  float bm = -1e30f;
  #pragma unroll
  for (int rg = 0; rg < 4; rg++){
    float s = 0.f;
    #pragma unroll
    for (int ct = 0; ct < 4; ct++)
      s += lrelu(acc[ct][rg] + a1v[ct]) * a2v[ct];
    s += __shfl_xor(s, 1); s += __shfl_xor(s, 2);
    s += __shfl_xor(s, 4); s += __shfl_xor(s, 8);
    int row = m0 + w * 16 + qd * 4 + rg;
    float sf = s + a2s;
    if (row < NN){
      bm = fmaxf(bm, sf);
      if (l16 == 0) scores[row] = sf;
    }
  }
  bm = fmaxf(bm, __shfl_xor(bm, 16));
  bm = fmaxf(bm, __shfl_xor(bm, 32));
  if (lane == 0) atomicMax(smax, (bm >= -1e29f) ?
      ((__float_as_uint(bm) & 0x80000000u) ? ~__float_as_uint(bm) : (__float_as_uint(bm) | 0x80000000u)) : 0u);
}

__device__ __forceinline__ float funmap(u32 m){
  union{u32 u; float f;} x;
  x.u = (m & 0x80000000u) ? (m ^ 0x80000000u) : ~m;
  return x.f;
}

__global__ void k_expsum(const float* __restrict__ scores, const u32* smax,
                         float* __restrict__ attnw, float* ssum, u32* flags){
  float mx = funmap(*smax);
  int gid = blockIdx.x * 256 + threadIdx.x;
  if (mx != mx){ if (gid == 0) atomicOr(flags, 32u); mx = 0.f; }
  float s = 0.f;
  bool bad = false;
  for (int i = gid; i < NN; i += 256 * 128){
    float e = __expf(scores[i] - mx);
    if (e != e){ bad = true; e = 0.f; }
    attnw[i] = e; s += e;
  }
  unsigned long long bal = __ballot(bad);
  if (bal && (threadIdx.x & 63) == 0) atomicOr(flags, 32u);
  for (int off = 32; off; off >>= 1) s += __shfl_down(s, off);
  if ((threadIdx.x & 63) == 0) unsafeAtomicAdd(ssum, s);
}

// ---------------- pooling: 32 nodes/block, per-run atomics (1563 blocks)
constexpr int POOL_CHUNK = 32;
__global__ __launch_bounds__(128) void k_pool(const float* __restrict__ emb,
                                              const float* __restrict__ attnw,
                                              const float* __restrict__ ssum,
                                              const int* __restrict__ batch,
                                              float* __restrict__ gemb, u32* flags){
  int t = threadIdx.x;
  int n0 = blockIdx.x * POOL_CHUNK;
  if (n0 >= NN) return;
  int n1 = min(n0 + POOL_CHUNK, NN);
  float sv = *ssum;
  bool bad = !(sv > 0.f) || (sv != sv);
  if (bad && t == 0 && blockIdx.x == 0) atomicOr(flags, 64u);
  float rs = bad ? 0.f : 1.0f / sv;
  int cur = batch[n0];
  float acc = 0.f;
  for (int n = n0; n < n1; n++){
    int b = batch[n];
    if (b != cur){ unsafeAtomicAdd(&gemb[cur * 128 + t], acc * rs); acc = 0.f; cur = b; }
    acc += emb[(size_t)n * 128 + t] * attnw[n];
  }
  unsafeAtomicAdd(&gemb[cur * 128 + t], acc * rs);
}

// ---------------- gembC[g][n] = gemb[g] . C1T_hi[n] + c1[n]  (64 x 128, K=128, f32)
__global__ void k_gembC(const float* __restrict__ gemb, const u16* __restrict__ wext,
                        float* __restrict__ gembC){
  int idx = blockIdx.x * 256 + threadIdx.x;
  if (idx >= 64 * 128) return;
  int g = idx >> 7, n = idx & 127;
  const float* gr = gemb + g * 128;
  const u16* wr = wext + WX_C1T + (size_t)n * 256 + 128;
  float s = 0.f;
  #pragma unroll 8
  for (int k = 0; k < 128; k++) s += gr[k] * bf2f(wr[k]);
  gembC[idx] = s + bf2f(wext[WX_c1 + n]);
}

// ---------------- final combiner: phase1 = embb @ C1_lo (bf16 A-frags direct)
// + gembC[batch] gather; Hs LDS relay; phase2 = Hs @ C2T; row L2 normalize.
// Diag sentinels folded into block 0 tail.
__global__ __launch_bounds__(256) void k_final_mfma(const u16* __restrict__ embb,
                                                    const float* __restrict__ gembC,
                                                    const int* __restrict__ batch,
                                                    const u16* __restrict__ wext,
                                                    void* __restrict__ outp,
                                                    const u32* md,
                                                    const u32* __restrict__ pairStart,
                                                    const u32* __restrict__ flags){
  __shared__ u16 Hs[64][136];   // 17.4 KB
  u32 fm = md[0];
  int m0 = blockIdx.x * 64;
  int tid = threadIdx.x;
  int w = tid >> 6, lane = tid & 63, qd = lane >> 4, l16 = lane & 15;
  int na = m0 + w * 16 + l16; if (na > NN - 1) na = NN - 1;
  const u16* arow = embb + (size_t)na * 128;

  f32x4 acc[8];
  #pragma unroll
  for (int j = 0; j < 8; j++) acc[j] = (f32x4){0.f,0.f,0.f,0.f};
  #pragma unroll
  for (int k0 = 0; k0 < 4; k0++){
    bf16x8 a = *(const bf16x8*)(arow + k0 * 32 + qd * 8);
    #pragma unroll
    for (int ct = 0; ct < 8; ct++){
      bf16x8 b = *(const bf16x8*)(wext + WX_C1T + (size_t)(ct * 16 + l16) * 256 + k0 * 32 + qd * 8);
      acc[ct] = __builtin_amdgcn_mfma_f32_16x16x32_bf16(a, b, acc[ct], 0, 0, 0);
    }
  }
  // epilogue 1: + gembC[batch[row]][col] (c1 folded in), lrelu, -> Hs
  int rbase = w * 16 + qd * 4;
  int gg[4];
  #pragma unroll
  for (int rg = 0; rg < 4; rg++){
    int node = m0 + rbase + rg; if (node > NN - 1) node = NN - 1;
    gg[rg] = batch[node];
  }
  #pragma unroll
  for (int ct = 0; ct < 8; ct++){
    int col = ct * 16 + l16;
    #pragma unroll
    for (int rg = 0; rg < 4; rg++){
      float h = acc[ct][rg] + gembC[gg[rg] * 128 + col];
      Hs[rbase + rg][col] = f2bf(lrelu(h));
    }
  }
  __syncthreads();
  f32x4 acc2[8];
  #pragma unroll
  for (int j = 0; j < 8; j++) acc2[j] = (f32x4){0.f,0.f,0.f,0.f};
  #pragma unroll
  for (int k0 = 0; k0 < 4; k0++){
    bf16x8 a = *(const bf16x8*)(&Hs[w * 16 + l16][k0 * 32 + qd * 8]);
    #pragma unroll
    for (int ct = 0; ct < 8; ct++){
      bf16x8 b = *(const bf16x8*)(wext + WX_C2T + (size_t)(ct * 16 + l16) * 128 + k0 * 32 + qd * 8);
      acc2[ct] = __builtin_amdgcn_mfma_f32_16x16x32_bf16(a, b, acc2[ct], 0, 0, 0);
    }
  }
  float c2v[8];
  #pragma unroll
  for (int ct = 0; ct < 8; ct++) c2v[ct] = bf2f(wext[WX_c2 + ct * 16 + l16]);
  #pragma unroll
  for (int rg = 0; rg < 4; rg++){
    float ss = 0.f;
    #pragma unroll
    for (int ct = 0; ct < 8; ct++){
      float o = acc2[ct][rg] + c2v[ct];
      ss += o * o;
    }
    ss += __shfl_xor(ss, 1); ss += __shfl_xor(ss, 2);
    ss += __shfl_xor(ss, 4); ss += __shfl_xor(ss, 8);
    float sc = 1.0f / fmaxf(sqrtf(ss), 1e-12f);
    int row = m0 + rbase + rg;
    if (row < NN){
      if (fm){
        float* op = (float*)outp;
        #pragma unroll
        for (int ct = 0; ct < 8; ct++)
          op[(size_t)row * 128 + ct * 16 + l16] = (acc2[ct][rg] + c2v[ct]) * sc;
      } else {
        u16* op = (u16*)outp;
        #pragma unroll
        for (int ct = 0; ct < 8; ct++)
          op[(size_t)row * 128 + ct * 16 + l16] = f2bf((acc2[ct][rg] + c2v[ct]) * sc);
      }
    }
  }
  // diag sentinels: block 0 owns rows 0..63 incl. output elems 0..8
  if (blockIdx.x == 0){
    __syncthreads();
    if (tid == 0){
      u32 f = flags[0];
      if (pairStart[NKEY] != (u32)EE) f |= 1u;
      for (int b = 0; b < 9; b++){
        if (f & (1u << b)){
          float s = (float)(131072 >> b);
          if (fm) ((float*)outp)[b] = s;
          else ((u16*)outp)[b] = f2bf(s);
        }
      }
    }
  }
}

__global__ void k_wsfail(u32* outp){ outp[0] = 0x43000000u; }

// ---------------- workspace layout (bytes)
constexpr size_t O_OUT   = 0;          // f32 N*128; pre-GEMM aliases: cursor/blockSum/blockBase
constexpr size_t O_H     = 25600000;
constexpr size_t O_XBF   = 38400000;   // bf16 x copy; reused as embb (bf16 L3 out) late
constexpr size_t O_WCAT  = 51200000;
constexpr size_t O_WEXT  = 52084736;
constexpr size_t O_EI    = 52200448;
constexpr size_t O_ET    = 56200448;
constexpr size_t O_BAT   = 58200448;
constexpr size_t O_SRC   = 58400448;   // 2 MB (src_s)
constexpr size_t O_PST   = 60400448;   // pairStart: (NKEY+1) u32 = 1,600,004 B; gembC in tail slack
constexpr size_t O_GEMBC = 62100448;   // 32 KB (inside O_PST..O_CNT slack)
constexpr size_t O_CNT   = 62400448;   // 1.6 MB
constexpr size_t O_SCO   = 65600448;
constexpr size_t O_AW    = 65800448;
constexpr size_t O_GEMB  = 66000448;
constexpr size_t O_STATS = 66033216;
constexpr size_t O_MISC  = 66035264;
constexpr size_t O_AGG   = 66035520;   // bf16 N*1024 = 102,400,000
constexpr size_t WS_NEED = 168435520;

extern "C" void kernel_launch(void* const* d_in, const int* in_sizes, int n_in,
                              void* d_out, int out_size, void* d_ws, size_t ws_size,
                              hipStream_t stream) {
  const void* x     = d_in[0];
  const void* ei    = d_in[1];
  const void* et    = d_in[2];
  const void* batch = d_in[3];
  const void* W1 = d_in[4],  *r1 = d_in[5],  *b1 = d_in[6];
  const void* W2 = d_in[7],  *r2 = d_in[8],  *b2 = d_in[9];
  const void* W3 = d_in[10], *r3 = d_in[11], *b3 = d_in[12];
  const void* g1 = d_in[13], *be1 = d_in[14];
  const void* g2 = d_in[15], *be2 = d_in[16];
  const void* A1 = d_in[17], *a1 = d_in[18];
  const void* A2 = d_in[19], *a2 = d_in[20];
  const void* C1 = d_in[21], *c1 = d_in[22];
  const void* C2 = d_in[23], *c2 = d_in[24];

  if (ws_size < WS_NEED){ k_wsfail<<<1, 1, 0, stream>>>((u32*)d_out); return; }
  char* ws = (char*)d_ws;
  float* out   = (float*)(ws + O_OUT);
  u16*   hbuf  = (u16*)(ws + O_H);
  u16*   xbf   = (u16*)(ws + O_XBF);
  u16*   wcat  = (u16*)(ws + O_WCAT);
  u16*   wext  = (u16*)(ws + O_WEXT);
  int*   ei_c  = (int*)(ws + O_EI);
  int*   et_c  = (int*)(ws + O_ET);
  int*   bat_c = (int*)(ws + O_BAT);
  u32*   src_s = (u32*)(ws + O_SRC);
  u32*   pairStart = (u32*)(ws + O_PST);
  float* gembC = (float*)(ws + O_GEMBC);
  u32*   cnt   = (u32*)(ws + O_CNT);
  float* sco   = (float*)(ws + O_SCO);
  float* aw    = (float*)(ws + O_AW);
  float* gemb  = (float*)(ws + O_GEMB);
  float* stats = (float*)(ws + O_STATS);
  u32*   misc  = (u32*)(ws + O_MISC);
  u16*   aggb  = (u16*)(ws + O_AGG);
  u32* cursor    = (u32*)(ws + O_OUT);
  u32* blockSum  = (u32*)(ws + O_OUT + 1600000);
  u32* blockBase = (u32*)(ws + O_OUT + 1604096);
  u32* smax = misc + 25;
  float* ssum = (float*)(misc + 26);
  u32* flags = misc + 27;
  u32* md = misc + 28;

  hipMemsetAsync(ws + O_CNT, 0, 1600000, stream);
  hipMemsetAsync(ws + O_GEMB, 0, 32768 + 2048 + 256, stream);

  k_detect<<<2, 256, 0, stream>>>(x, et, md);
  k_cvt<<<12305, 256, 0, stream>>>(ei, et, batch, x, ei_c, et_c, bat_c, xbf, cnt, md, flags);
  k_wprep<<<1955, 256, 0, stream>>>(W1, r1, W2, r2, W3, r3,
                                    A1, a1, A2, a2, C1, c1, C2, c2, wcat, wext, md, flags);

  k_pairA<<<PAIR_B, 256, 0, stream>>>(cnt, blockSum);
  k_pairB<<<1, 64, 0, stream>>>(blockSum, blockBase);
  k_pairC<<<PAIR_B, 256, 0, stream>>>(cnt, blockBase, pairStart, cursor);
  k_sort3<<<(EE + 255) / 256, 256, 0, stream>>>(ei_c, et_c, pairStart, cursor, src_s);

  const void* bias[3] = {b1, b2, b3};
  const void* gam[2] = {g1, g2};
  const void* bet[2] = {be1, be2};
  const u16* hin = xbf;
  for (int L = 0; L < 3; L++){
    const u16* wT = wcat + (size_t)L * 128 * 1152;
    k_agg<<<(NN + 3) / 4, 256, 0, stream>>>(hin, pairStart, src_s, aggb);
    k_gemm_big<<<1568, 256, 0, stream>>>(hin, aggb, wT, bias[L], out, md,
                                         stats + (L < 2 ? L * 256 : 0), (L < 2) ? 1 : 0,
                                         (L == 2) ? xbf : (u16*)nullptr);
    if (L < 2){
      k_bnapply<<<6250, 256, 0, stream>>>(out, stats + L * 256, gam[L], bet[L], hbuf, md, flags, 4u << L);
      hin = hbuf;
    }
  }
  k_scores_mfma<<<(NN + 63) / 64, 256, 0, stream>>>(xbf, wext, sco, smax);
  k_expsum<<<128, 256, 0, stream>>>(sco, smax, aw, ssum, flags);
  k_pool<<<(NN + POOL_CHUNK - 1) / POOL_CHUNK, 128, 0, stream>>>(out, aw, ssum, bat_c, gemb, flags);
  k_gembC<<<32, 256, 0, stream>>>(gemb, wext, gembC);
  k_final_mfma<<<(NN + 63) / 64, 256, 0, stream>>>(xbf, gembC, bat_c, wext, d_out, md,
                                                   pairStart, flags);
}

// Round 15
// 599.199 us; speedup vs baseline: 1.0551x; 1.0176x over previous
//
#include <hip/hip_runtime.h>
#include <hip/hip_bf16.h>

typedef unsigned int u32;
typedef unsigned short u16;
typedef __bf16 bf16_t;
typedef bf16_t bf16x8 __attribute__((ext_vector_type(8)));
typedef float f32x4 __attribute__((ext_vector_type(4)));

constexpr int NN = 50000;
constexpr int EE = 500000;
constexpr int RR = 8;
constexpr int NKEY = RR * NN;               // 400000
constexpr int PAIR_B = (NKEY + 511) / 512;  // 782

// wext element offsets (bf16 elems)
constexpr int WX_A1T = 0;       // [64][128]
constexpr int WX_C1T = 8192;    // [128][256]
constexpr int WX_C2T = 40960;   // [128][128]
constexpr int WX_A2  = 57344;   // [64]
constexpr int WX_a1  = 57408;   // [64]
constexpr int WX_c1  = 57472;   // [128]
constexpr int WX_c2  = 57600;   // [128]
constexpr int WX_a2s = 57728;   // [1]
constexpr int WX_TOT = 57729;

__device__ __forceinline__ float bf2f(u32 v){
  union { u32 u; float f; } x; x.u = (v & 0xFFFFu) << 16; return x.f;
}
__device__ __forceinline__ u16 f2bf(float f){
  union { u32 u; float f; } x; x.f = f;
  u32 r = x.u + 0x7FFFu + ((x.u >> 16) & 1u);
  return (u16)(r >> 16);
}
__device__ __forceinline__ float lrelu(float x){ return x > 0.f ? x : 0.1f * x; }
__device__ __forceinline__ float ldf(const void* p, int i, u32 fm){
  return fm ? ((const float*)p)[i] : bf2f(((const u16*)p)[i]);
}
// direct global->LDS DMA, 16B per lane; LDS dest is wave-uniform base + lane*16
__device__ __forceinline__ void gl_lds16(const u16* g, u16* l){
  __builtin_amdgcn_global_load_lds((const __attribute__((address_space(1))) u32*)g,
                                   (__attribute__((address_space(3))) u32*)l, 16, 0, 0);
}

// ---------------- dtype detectors (merged) ----------------
__global__ void k_detect(const void* x, const void* et, u32* md){
  __shared__ u32 c;
  if (threadIdx.x == 0) c = 0;
  __syncthreads();
  u32 loc = 0;
  if (blockIdx.x == 0){
    const u16* p = (const u16*)x;
    for (int j = 0; j < 16; j++){
      u16 v = p[threadIdx.x * 16 + j];
      u32 e = (v >> 7) & 0xFF;
      if (e >= 0xFD) loc++;
    }
    atomicAdd(&c, loc);
    __syncthreads();
    if (threadIdx.x == 0) md[0] = (c >= 4) ? 1u : 0u;
  } else {
    const int* p = (const int*)et;
    for (int j = 0; j < 8; j++){
      int idx = 2 * (threadIdx.x * 8 + j) + 1;
      if (p[idx] != 0) loc++;
    }
    atomicAdd(&c, loc);
    __syncthreads();
    if (threadIdx.x == 0) md[1] = (c == 0) ? 1u : 0u;
  }
}

// ---------------- int conversion + x conversion (merged) + fused (dst,rel) count
// blocks [0,6055): int paths; blocks [6055,12305): x->bf16
__global__ void k_cvt(const void* ei, const void* et, const void* bat, const void* x,
                      int* ei_c, int* et_c, int* bat_c, u16* xb,
                      u32* __restrict__ cnt, const u32* md, u32* flags){
  if (blockIdx.x < 6055){
    u32 im = md[1];
    int i = blockIdx.x * 256 + threadIdx.x;
    if (i < EE){
      const int* p = (const int*)ei;
      ei_c[i] = im ? p[2 * i] : p[i];
    } else if (i < 2 * EE){
      int j = i - EE;
      const int* p = (const int*)ei;
      const int* pt = (const int*)et;
      int d = im ? p[2 * i] : p[i];
      int r = im ? pt[2 * j] : pt[j];
      ei_c[i] = d;
      atomicAdd(&cnt[d * RR + r], 1u);
    } else if (i < 3 * EE){
      int j = i - 2 * EE;
      const int* p = (const int*)et;
      et_c[j] = im ? p[2 * j] : p[j];
    } else if (i < 3 * EE + NN){
      int j = i - 3 * EE;
      const int* p = (const int*)bat;
      bat_c[j] = im ? p[2 * j] : p[j];
    }
  } else {
    u32 fm = md[0];
    int i4 = ((blockIdx.x - 6055) * 256 + threadIdx.x) * 4;
    if (i4 >= NN * 128) return;
    float v[4];
    if (fm){
      float4 f = *(const float4*)((const float*)x + i4);
      v[0]=f.x; v[1]=f.y; v[2]=f.z; v[3]=f.w;
    } else {
      uint2 u = *(const uint2*)((const u16*)x + i4);
      v[0]=bf2f(u.x); v[1]=bf2f(u.x>>16); v[2]=bf2f(u.y); v[3]=bf2f(u.y>>16);
    }
    bool bad = false;
    u16 o[4];
    for (int j = 0; j < 4; j++){
      if (v[j] != v[j]){ bad = true; v[j] = 0.f; }
      o[j] = f2bf(v[j]);
    }
    unsigned long long bal = __ballot(bad);
    if (bal && (threadIdx.x & 63) == 0) atomicOr(flags, 2u);
    uint2 st;
    st.x = (u32)o[0] | ((u32)o[1] << 16);
    st.y = (u32)o[2] | ((u32)o[3] << 16);
    *(uint2*)(xb + i4) = st;
  }
}

// ---------------- weight transpose + small-MLP weight prep (merged)
// blocks [0,1728): wcatT[L][n][k'] (k'<1024: k'=c*8+r -> W[L][r*128+c][n]; else root)
// blocks [1728,1955): wext
__global__ void k_wprep(const void* W1, const void* r1, const void* W2, const void* r2,
                        const void* W3, const void* r3,
                        const void* A1, const void* a1, const void* A2, const void* a2,
                        const void* C1, const void* c1, const void* C2, const void* c2,
                        u16* wcatT, u16* wext, const u32* md, u32* flags){
  u32 fm = md[0];
  if (blockIdx.x < 1728){
    int idx = blockIdx.x * 256 + threadIdx.x;
    int L = idx / (128 * 1152);
    int rem = idx % (128 * 1152);
    int n = rem / 1152, k = rem % 1152;
    const void* W  = (L == 0) ? W1 : ((L == 1) ? W2 : W3);
    const void* rt = (L == 0) ? r1 : ((L == 1) ? r2 : r3);
    float v;
    if (k < 1024){
      int r = k & 7, c = k >> 3;
      v = ldf(W, (r * 128 + c) * 128 + n, fm);
    } else {
      v = ldf(rt, (k - 1024) * 128 + n, fm);
    }
    if (v != v){ v = 0.f; atomicOr(flags, 2u); }
    wcatT[idx] = f2bf(v);
  } else {
    int idx = (blockIdx.x - 1728) * 256 + threadIdx.x;
    if (idx >= WX_TOT) return;
    float v;
    if (idx < WX_C1T){
      int n = idx >> 7, k = idx & 127;
      v = ldf(A1, k * 64 + n, fm);
    } else if (idx < WX_C2T){
      int j = idx - WX_C1T; int n = j >> 8, k = j & 255;
      v = ldf(C1, k * 128 + n, fm);
    } else if (idx < WX_A2){
      int j = idx - WX_C2T; int n = j >> 7, k = j & 127;
      v = ldf(C2, k * 128 + n, fm);
    } else if (idx < WX_a1){ v = ldf(A2, idx - WX_A2, fm); }
    else if (idx < WX_c1){ v = ldf(a1, idx - WX_a1, fm); }
    else if (idx < WX_c2){ v = ldf(c1, idx - WX_c1, fm); }
    else if (idx < WX_a2s){ v = ldf(c2, idx - WX_c2, fm); }
    else { v = ldf(a2, 0, fm); }
    wext[idx] = f2bf(v);
  }
}

// ---------------- (dst,rel) counting sort: key = d*RR + r (dst-major) ----------------
__global__ void k_pairA(const u32* __restrict__ cnt, u32* __restrict__ blockSum){
  __shared__ u32 sd[256];
  int b = blockIdx.x, t = threadIdx.x;
  u32 s = 0;
  for (int j = 0; j < 2; j++){
    int key = b * 512 + t * 2 + j;
    if (key < NKEY) s += cnt[key];
  }
  sd[t] = s; __syncthreads();
  for (int off = 128; off; off >>= 1){ if (t < off) sd[t] += sd[t + off]; __syncthreads(); }
  if (t == 0) blockSum[b] = sd[0];
}
__global__ void k_pairB(const u32* __restrict__ blockSum, u32* __restrict__ blockBase){
  int lane = threadIdx.x;   // 64
  u32 loc[13]; u32 s = 0;
  for (int j = 0; j < 13; j++){
    int b = lane * 13 + j;
    u32 v = (b < PAIR_B) ? blockSum[b] : 0u;
    loc[j] = s; s += v;
  }
  u32 tot = s;
  for (int off = 1; off < 64; off <<= 1){
    u32 x = __shfl_up(tot, off);
    if (lane >= off) tot += x;
  }
  u32 excl = tot - s;
  for (int j = 0; j < 13; j++){
    int b = lane * 13 + j;
    if (b < PAIR_B) blockBase[b] = excl + loc[j];
  }
}
__global__ void k_pairC(const u32* __restrict__ cnt, const u32* __restrict__ blockBase,
                        u32* __restrict__ pairStart, u32* __restrict__ cursor){
  __shared__ u32 sd[256];
  int b = blockIdx.x, t = threadIdx.x;
  int k0 = b * 512 + t * 2;
  u32 v0 = 0, v1 = 0;
  if (k0 < NKEY) v0 = cnt[k0];
  if (k0 + 1 < NKEY) v1 = cnt[k0 + 1];
  sd[t] = v0 + v1; __syncthreads();
  for (int off = 1; off < 256; off <<= 1){
    u32 x = (t >= off) ? sd[t - off] : 0u;
    __syncthreads();
    sd[t] += x;
    __syncthreads();
  }
  u32 excl = sd[t] - (v0 + v1);
  u32 base = blockBase[b] + excl;
  if (k0 < NKEY){ pairStart[k0] = base; cursor[k0] = 0u; }
  if (k0 + 1 < NKEY){ pairStart[k0 + 1] = base + v0; cursor[k0 + 1] = 0u; }
  if (k0 + 1 == NKEY - 1) pairStart[NKEY] = base + v0 + v1;   // genuine scan total
}
__global__ void k_sort3(const int* __restrict__ ei, const int* __restrict__ et,
                        const u32* __restrict__ pairStart, u32* __restrict__ cursor,
                        u32* __restrict__ src_s){
  int e = blockIdx.x * 256 + threadIdx.x;
  if (e >= EE) return;
  int r = et[e], d = ei[EE + e];
  u32 key = (u32)d * RR + (u32)r;
  u32 p = pairStart[key] + atomicAdd(&cursor[key], 1u);
  src_s[p] = (u32)ei[e];
}

// ---------------- aggregation: one wave per dst node, all 8 relations
// agg layout: [d][c][r] (elem = c*8+r). Preloaded src broadcast + unroll-2 gather;
// per-lane 2 cols x 8 rel -> one 32B contiguous store (2KB/node coalesced).
__global__ __launch_bounds__(256) void k_agg(const u16* __restrict__ h,
                                             const u32* __restrict__ pairStart,
                                             const u32* __restrict__ src_s,
                                             u16* __restrict__ agg){
  int d = blockIdx.x * 4 + (threadIdx.x >> 6);
  if (d >= NN) return;
  int lane = threadIdx.x & 63;
  const uint4* p4 = (const uint4*)(pairStart + d * 8);
  uint4 q0 = p4[0], q1 = p4[1];
  u32 ps[9];
  ps[0]=q0.x; ps[1]=q0.y; ps[2]=q0.z; ps[3]=q0.w;
  ps[4]=q1.x; ps[5]=q1.y; ps[6]=q1.z; ps[7]=q1.w;
  ps[8]=pairStart[d * 8 + 8];
  u32 jb = ps[0], je = ps[8];
  // coalesced preload of up to 64 src indices for the whole node
  u32 pre = 0;
  if (jb + lane < je) pre = src_s[jb + lane];
  const u16* hb = h + lane * 2;
  u32 ou[8] = {0,0,0,0,0,0,0,0};
  #pragma unroll
  for (int r = 0; r < 8; r++){
    u32 s = ps[r], e = ps[r + 1];
    float a0 = 0.f, a1 = 0.f, b0 = 0.f, b1 = 0.f;
    u32 j = s;
    for (; j + 1 < e; j += 2){
      u32 i0 = j - jb;
      u32 s0 = (i0 < 64) ? __shfl(pre, (int)i0) : src_s[j];
      u32 s1 = (i0 + 1 < 64) ? __shfl(pre, (int)(i0 + 1)) : src_s[j + 1];
      u32 v0 = *(const u32*)(hb + (size_t)s0 * 128);
      u32 v1 = *(const u32*)(hb + (size_t)s1 * 128);
      a0 += bf2f(v0); a1 += bf2f(v0 >> 16);
      b0 += bf2f(v1); b1 += bf2f(v1 >> 16);
    }
    if (j < e){
      u32 i0 = j - jb;
      u32 s0 = (i0 < 64) ? __shfl(pre, (int)i0) : src_s[j];
      u32 v0 = *(const u32*)(hb + (size_t)s0 * 128);
      a0 += bf2f(v0); a1 += bf2f(v0 >> 16);
    }
    a0 += b0; a1 += b1;
    int c = (int)(e - s);
    float sc = 1.0f / (float)max(c, 1);
    u32 m0 = (u32)f2bf(a0 * sc), m1 = (u32)f2bf(a1 * sc);
    ou[r >> 1]       |= m0 << ((r & 1) * 16);
    ou[4 + (r >> 1)] |= m1 << ((r & 1) * 16);
  }
  uint4* dst = (uint4*)(agg + (size_t)d * 1024 + lane * 16);
  dst[0] = make_uint4(ou[0], ou[1], ou[2], ou[3]);
  dst[1] = make_uint4(ou[4], ou[5], ou[6], ou[7]);
}

// ---------------- big GEMM: out[N,128] = [agg | h] (K=1152) @ wcatT + bias
// Split-N with XCD-aware pairing (R12): grid 1568 (98x16); mt=(g>>4)*8+(g&7),
// nh=(g>>3)&1. Two-subtile K-step (BK=128 as 2x64 proven-swizzle tiles): one
// drain covers 12 in-flight loads + 16 MFMAs; 18 barriers instead of 36.
// Conflict-free per-64-tile swizzle (R9's 128-wide row conflicts avoided).
__global__ __launch_bounds__(256) void k_gemm_big(const u16* __restrict__ h,
                                                  const u16* __restrict__ agg,
                                                  const u16* __restrict__ wT,
                                                  const void* __restrict__ bias,
                                                  float* __restrict__ out, const u32* md,
                                                  float* __restrict__ stats, int do_stats,
                                                  u16* __restrict__ embb){
  __shared__ u16 As[2][64][64];   // 2 x 8 KB; slot (row,c8) holds global (row, c8^(row&7))
  __shared__ u16 Bs[2][64][64];   // 2 x 8 KB
  u32 fm = md[0];
  int g = blockIdx.x;
  int mt = (g >> 4) * 8 + (g & 7);  // m-tile id; bids g and g+8 share mt and XCD
  int nh = (g >> 3) & 1;            // this block's 64-col output half
  int m0 = mt * 64;
  int tid = threadIdx.x;
  int w = tid >> 6, lane = tid & 63, qd = lane >> 4, l16 = lane & 15;

  int rin = lane >> 3;              // row within 8-row chunk
  int sc8 = (lane & 7) ^ rin;       // pre-swizzled source col8 (involution)

  // A: 2 chunks/wave (8 rows x 64 cols = 1 KB each); B: 2 chunks/wave
  const u16* agA[2]; const u16* hA[2];
  #pragma unroll
  for (int i = 0; i < 2; i++){
    int row = (w * 2 + i) * 8 + rin;
    int node = m0 + row; if (node > NN - 1) node = NN - 1;
    agA[i] = agg + (size_t)node * 1024 + sc8 * 8;
    hA[i]  = h + (size_t)node * 128 + sc8 * 8;
  }
  const u16* wB[2];
  #pragma unroll
  for (int i = 0; i < 2; i++){
    int row = (w * 2 + i) * 8 + rin;        // n-col within half
    wB[i] = wT + (size_t)(nh * 64 + row) * 1152 + sc8 * 8;
  }

  auto stage = [&](int k0, int b){
    if (k0 < 1024){
      gl_lds16(agA[0] + k0, &As[b][(w * 2 + 0) * 8][0]);
      gl_lds16(agA[1] + k0, &As[b][(w * 2 + 1) * 8][0]);
    } else {
      gl_lds16(hA[0] + (k0 - 1024), &As[b][(w * 2 + 0) * 8][0]);
      gl_lds16(hA[1] + (k0 - 1024), &As[b][(w * 2 + 1) * 8][0]);
    }
    gl_lds16(wB[0] + k0, &Bs[b][(w * 2 + 0) * 8][0]);
    gl_lds16(wB[1] + k0, &Bs[b][(w * 2 + 1) * 8][0]);
  };

  f32x4 acc[4];
  #pragma unroll
  for (int j = 0; j < 4; j++) acc[j] = (f32x4){0.f,0.f,0.f,0.f};

  int sw = (l16 & 7) << 3;   // read-side XOR in elems
  for (int t = 0; t < 9; t++){
    int k0 = t * 128;
    __syncthreads();                       // prev MFMA reads done; LDS free
    stage(k0, 0);
    stage(k0 + 64, 1);
    __syncthreads();                       // vmcnt(0) drain -> both sub-tiles ready
    #pragma unroll
    for (int b = 0; b < 2; b++){
      #pragma unroll
      for (int kk = 0; kk < 64; kk += 32){
        bf16x8 a = *(const bf16x8*)(&As[b][w * 16 + l16][(kk + qd * 8) ^ sw]);
        #pragma unroll
        for (int ct = 0; ct < 4; ct++){
          bf16x8 bb = *(const bf16x8*)(&Bs[b][ct * 16 + l16][(kk + qd * 8) ^ sw]);
          acc[ct] = __builtin_amdgcn_mfma_f32_16x16x32_bf16(a, bb, acc[ct], 0, 0, 0);
        }
      }
    }
  }

  float sarr[4], s2arr[4];
  #pragma unroll
  for (int ct = 0; ct < 4; ct++){
    int col = nh * 64 + ct * 16 + l16;
    float bv = ldf(bias, col, fm);
    float s = 0.f, s2 = 0.f;
    int rbase = m0 + w * 16 + qd * 4;
    #pragma unroll
    for (int rg = 0; rg < 4; rg++){
      int node = rbase + rg;
      if (node < NN){
        float v = acc[ct][rg] + bv;
        out[(size_t)node * 128 + col] = v;
        if (embb) embb[(size_t)node * 128 + col] = f2bf(v);
        s += v; s2 += v * v;
      }
    }
    s  += __shfl_xor(s, 16);  s  += __shfl_xor(s, 32);
    s2 += __shfl_xor(s2, 16); s2 += __shfl_xor(s2, 32);
    sarr[ct] = s; s2arr[ct] = s2;
  }
  if (do_stats){
    float* red = (float*)&As[0][0][0];     // 512 floats = 2 KB (As is 16 KB)
    __syncthreads();                       // all MFMA reads of As done
    if (qd == 0){
      #pragma unroll
      for (int ct = 0; ct < 4; ct++){
        red[w * 128 + ct * 16 + l16] = sarr[ct];
        red[w * 128 + 64 + ct * 16 + l16] = s2arr[ct];
      }
    }
    __syncthreads();
    if (tid < 128){
      float v = red[tid] + red[128 + tid] + red[256 + tid] + red[384 + tid];
      int which = tid >> 6, colh = tid & 63;
      unsafeAtomicAdd(&stats[which * 128 + nh * 64 + colh], v);
    }
  }
}

__global__ void k_bnapply(const float* __restrict__ out, const float* __restrict__ stats,
                          const void* __restrict__ g, const void* __restrict__ beta,
                          u16* __restrict__ hout, const u32* md, u32* flags, u32 layerbit){
  u32 fm = md[0];
  int idx = (blockIdx.x * 256 + threadIdx.x) * 4;
  if (idx >= NN * 128) return;
  int col = idx & 127;
  float4 v = *(const float4*)(out + idx);
  float vv[4] = {v.x, v.y, v.z, v.w};
  bool bad = false;
  u16 o[4];
  for (int j = 0; j < 4; j++){
    int c = col + j;
    float mu = stats[c] * (1.0f / NN);
    float var = fmaxf(stats[128 + c] * (1.0f / NN) - mu * mu, 0.f);
    float sc = ldf(g, c, fm) * rsqrtf(var + 1e-5f);
    float sh = ldf(beta, c, fm) - mu * sc;
    float r = vv[j] * sc + sh;
    if (r != r || sc != sc){ bad = true; r = 0.f; }
    o[j] = f2bf(lrelu(r));
  }
  unsigned long long bal = __ballot(bad);
  if (bal && (threadIdx.x & 63) == 0) atomicOr(flags, layerbit);
  uint2 st;
  st.x = (u32)o[0] | ((u32)o[1] << 16);
  st.y = (u32)o[2] | ((u32)o[3] << 16);
  *(uint2*)(hout + idx) = st;
}

// ---------------- attention scores via MFMA: no LDS, A-frags direct from bf16 emb,
// fused per-block score max (atomicMax into smax). BM=64, 782 blocks.
__global__ __launch_bounds__(256) void k_scores_mfma(const u16* __restrict__ embb,
                                                     const u16* __restrict__ wext,
                                                     float* __restrict__ scores, u32* smax){
  int m0 = blockIdx.x * 64;
  int tid = threadIdx.x;
  int w = tid >> 6, lane = tid & 63, qd = lane >> 4, l16 = lane & 15;
  int na = m0 + w * 16 + l16; if (na > NN - 1) na = NN - 1;
  const u16* arow = embb + (size_t)na * 128;
  f32x4 acc[4];
  #pragma unroll
  for (int j = 0; j < 4; j++) acc[j] = (f32x4){0.f,0.f,0.f,0.f};
  #pragma unroll
  for (int k0 = 0; k0 < 4; k0++){
    bf16x8 a = *(const bf16x8*)(arow + k0 * 32 + qd * 8);
    #pragma unroll
    for (int ct = 0; ct < 4; ct++){
      bf16x8 b = *(const bf16x8*)(wext + WX_A1T + (size_t)(ct * 16 + l16) * 128 + k0 * 32 + qd * 8);
      acc[ct] = __builtin_amdgcn_mfma_f32_16x16x32_bf16(a, b, acc[ct], 0, 0, 0);
    }
  }
  float a1v[4], a2v[4];
  #pragma unroll
  for (int ct = 0; ct < 4; ct++){
    a1v[ct] = bf2f(wext[WX_a1 + ct * 16 + l16]);
    a2v[ct] = bf2f(wext[WX_A2 + ct * 16 + l16]);
  }
  float a2s = bf2f(wext[WX_a2s]);
  float bm = -1e30f;
  #pragma unroll
  for (int rg = 0; rg < 4; rg++){
    float s = 0.f;
    #pragma unroll
    for (int ct = 0; ct < 4; ct++)
      s += lrelu(acc[ct][rg] + a1v[ct]) * a2v[ct];
    s += __shfl_xor(s, 1); s += __shfl_xor(s, 2);
    s += __shfl_xor(s, 4); s += __shfl_xor(s, 8);
    int row = m0 + w * 16 + qd * 4 + rg;
    float sf = s + a2s;
    if (row < NN){
      bm = fmaxf(bm, sf);
      if (l16 == 0) scores[row] = sf;
    }
  }
  bm = fmaxf(bm, __shfl_xor(bm, 16));
  bm = fmaxf(bm, __shfl_xor(bm, 32));
  if (lane == 0) atomicMax(smax, (bm >= -1e29f) ?
      ((__float_as_uint(bm) & 0x80000000u) ? ~__float_as_uint(bm) : (__float_as_uint(bm) | 0x80000000u)) : 0u);
}

__device__ __forceinline__ float funmap(u32 m){
  union{u32 u; float f;} x;
  x.u = (m & 0x80000000u) ? (m ^ 0x80000000u) : ~m;
  return x.f;
}

__global__ void k_expsum(const float* __restrict__ scores, const u32* smax,
                         float* __restrict__ attnw, float* ssum, u32* flags){
  float mx = funmap(*smax);
  int gid = blockIdx.x * 256 + threadIdx.x;
  if (mx != mx){ if (gid == 0) atomicOr(flags, 32u); mx = 0.f; }
  float s = 0.f;
  bool bad = false;
  for (int i = gid; i < NN; i += 256 * 128){
    float e = __expf(scores[i] - mx);
    if (e != e){ bad = true; e = 0.f; }
    attnw[i] = e; s += e;
  }
  unsigned long long bal = __ballot(bad);
  if (bal && (threadIdx.x & 63) == 0) atomicOr(flags, 32u);
  for (int off = 32; off; off >>= 1) s += __shfl_down(s, off);
  if ((threadIdx.x & 63) == 0) unsafeAtomicAdd(ssum, s);
}

// ---------------- pooling: 32 nodes/block, per-run atomics (1563 blocks)
constexpr int POOL_CHUNK = 32;
__global__ __launch_bounds__(128) void k_pool(const float* __restrict__ emb,
                                              const float* __restrict__ attnw,
                                              const float* __restrict__ ssum,
                                              const int* __restrict__ batch,
                                              float* __restrict__ gemb, u32* flags){
  int t = threadIdx.x;
  int n0 = blockIdx.x * POOL_CHUNK;
  if (n0 >= NN) return;
  int n1 = min(n0 + POOL_CHUNK, NN);
  float sv = *ssum;
  bool bad = !(sv > 0.f) || (sv != sv);
  if (bad && t == 0 && blockIdx.x == 0) atomicOr(flags, 64u);
  float rs = bad ? 0.f : 1.0f / sv;
  int cur = batch[n0];
  float acc = 0.f;
  for (int n = n0; n < n1; n++){
    int b = batch[n];
    if (b != cur){ unsafeAtomicAdd(&gemb[cur * 128 + t], acc * rs); acc = 0.f; cur = b; }
    acc += emb[(size_t)n * 128 + t] * attnw[n];
  }
  unsafeAtomicAdd(&gemb[cur * 128 + t], acc * rs);
}

// ---------------- gembC[g][n] = gemb[g] . C1T_hi[n] + c1[n]  (64 x 128, K=128, f32)
__global__ void k_gembC(const float* __restrict__ gemb, const u16* __restrict__ wext,
                        float* __restrict__ gembC){
  int idx = blockIdx.x * 256 + threadIdx.x;
  if (idx >= 64 * 128) return;
  int g = idx >> 7, n = idx & 127;
  const float* gr = gemb + g * 128;
  const u16* wr = wext + WX_C1T + (size_t)n * 256 + 128;
  float s = 0.f;
  #pragma unroll 8
  for (int k = 0; k < 128; k++) s += gr[k] * bf2f(wr[k]);
  gembC[idx] = s + bf2f(wext[WX_c1 + n]);
}

// ---------------- final combiner: phase1 = embb @ C1_lo (bf16 A-frags direct)
// + gembC[batch] gather; Hs LDS relay; phase2 = Hs @ C2T; row L2 normalize.
// Diag sentinels folded into block 0 tail.
__global__ __launch_bounds__(256) void k_final_mfma(const u16* __restrict__ embb,
                                                    const float* __restrict__ gembC,
                                                    const int* __restrict__ batch,
                                                    const u16* __restrict__ wext,
                                                    void* __restrict__ outp,
                                                    const u32* md,
                                                    const u32* __restrict__ pairStart,
                                                    const u32* __restrict__ flags){
  __shared__ u16 Hs[64][136];   // 17.4 KB
  u32 fm = md[0];
  int m0 = blockIdx.x * 64;
  int tid = threadIdx.x;
  int w = tid >> 6, lane = tid & 63, qd = lane >> 4, l16 = lane & 15;
  int na = m0 + w * 16 + l16; if (na > NN - 1) na = NN - 1;
  const u16* arow = embb + (size_t)na * 128;

  f32x4 acc[8];
  #pragma unroll
  for (int j = 0; j < 8; j++) acc[j] = (f32x4){0.f,0.f,0.f,0.f};
  #pragma unroll
  for (int k0 = 0; k0 < 4; k0++){
    bf16x8 a = *(const bf16x8*)(arow + k0 * 32 + qd * 8);
    #pragma unroll
    for (int ct = 0; ct < 8; ct++){
      bf16x8 b = *(const bf16x8*)(wext + WX_C1T + (size_t)(ct * 16 + l16) * 256 + k0 * 32 + qd * 8);
      acc[ct] = __builtin_amdgcn_mfma_f32_16x16x32_bf16(a, b, acc[ct], 0, 0, 0);
    }
  }
  // epilogue 1: + gembC[batch[row]][col] (c1 folded in), lrelu, -> Hs
  int rbase = w * 16 + qd * 4;
  int gg[4];
  #pragma unroll
  for (int rg = 0; rg < 4; rg++){
    int node = m0 + rbase + rg; if (node > NN - 1) node = NN - 1;
    gg[rg] = batch[node];
  }
  #pragma unroll
  for (int ct = 0; ct < 8; ct++){
    int col = ct * 16 + l16;
    #pragma unroll
    for (int rg = 0; rg < 4; rg++){
      float h = acc[ct][rg] + gembC[gg[rg] * 128 + col];
      Hs[rbase + rg][col] = f2bf(lrelu(h));
    }
  }
  __syncthreads();
  f32x4 acc2[8];
  #pragma unroll
  for (int j = 0; j < 8; j++) acc2[j] = (f32x4){0.f,0.f,0.f,0.f};
  #pragma unroll
  for (int k0 = 0; k0 < 4; k0++){
    bf16x8 a = *(const bf16x8*)(&Hs[w * 16 + l16][k0 * 32 + qd * 8]);
    #pragma unroll
    for (int ct = 0; ct < 8; ct++){
      bf16x8 b = *(const bf16x8*)(wext + WX_C2T + (size_t)(ct * 16 + l16) * 128 + k0 * 32 + qd * 8);
      acc2[ct] = __builtin_amdgcn_mfma_f32_16x16x32_bf16(a, b, acc2[ct], 0, 0, 0);
    }
  }
  float c2v[8];
  #pragma unroll
  for (int ct = 0; ct < 8; ct++) c2v[ct] = bf2f(wext[WX_c2 + ct * 16 + l16]);
  #pragma unroll
  for (int rg = 0; rg < 4; rg++){
    float ss = 0.f;
    #pragma unroll
    for (int ct = 0; ct < 8; ct++){
      float o = acc2[ct][rg] + c2v[ct];
      ss += o * o;
    }
    ss += __shfl_xor(ss, 1); ss += __shfl_xor(ss, 2);
    ss += __shfl_xor(ss, 4); ss += __shfl_xor(ss, 8);
    float sc = 1.0f / fmaxf(sqrtf(ss), 1e-12f);
    int row = m0 + rbase + rg;
    if (row < NN){
      if (fm){
        float* op = (float*)outp;
        #pragma unroll
        for (int ct = 0; ct < 8; ct++)
          op[(size_t)row * 128 + ct * 16 + l16] = (acc2[ct][rg] + c2v[ct]) * sc;
      } else {
        u16* op = (u16*)outp;
        #pragma unroll
        for (int ct = 0; ct < 8; ct++)
          op[(size_t)row * 128 + ct * 16 + l16] = f2bf((acc2[ct][rg] + c2v[ct]) * sc);
      }
    }
  }
  // diag sentinels: block 0 owns rows 0..63 incl. output elems 0..8
  if (blockIdx.x == 0){
    __syncthreads();
    if (tid == 0){
      u32 f = flags[0];
      if (pairStart[NKEY] != (u32)EE) f |= 1u;
      for (int b = 0; b < 9; b++){
        if (f & (1u << b)){
          float s = (float)(131072 >> b);
          if (fm) ((float*)outp)[b] = s;
          else ((u16*)outp)[b] = f2bf(s);
        }
      }
    }
  }
}

__global__ void k_wsfail(u32* outp){ outp[0] = 0x43000000u; }

// ---------------- workspace layout (bytes)
constexpr size_t O_OUT   = 0;          // f32 N*128; pre-GEMM aliases: cursor/blockSum/blockBase
constexpr size_t O_H     = 25600000;
constexpr size_t O_XBF   = 38400000;   // bf16 x copy; reused as embb (bf16 L3 out) late
constexpr size_t O_WCAT  = 51200000;
constexpr size_t O_WEXT  = 52084736;
constexpr size_t O_EI    = 52200448;
constexpr size_t O_ET    = 56200448;
constexpr size_t O_BAT   = 58200448;
constexpr size_t O_SRC   = 58400448;   // 2 MB (src_s)
constexpr size_t O_PST   = 60400448;   // pairStart: (NKEY+1) u32 = 1,600,004 B; gembC in tail slack
constexpr size_t O_GEMBC = 62100448;   // 32 KB (inside O_PST..O_CNT slack)
constexpr size_t O_CNT   = 62400448;   // 1.6 MB
constexpr size_t O_SCO   = 65600448;
constexpr size_t O_AW    = 65800448;
constexpr size_t O_GEMB  = 66000448;
constexpr size_t O_STATS = 66033216;
constexpr size_t O_MISC  = 66035264;
constexpr size_t O_AGG   = 66035520;   // bf16 N*1024 = 102,400,000
constexpr size_t WS_NEED = 168435520;

extern "C" void kernel_launch(void* const* d_in, const int* in_sizes, int n_in,
                              void* d_out, int out_size, void* d_ws, size_t ws_size,
                              hipStream_t stream) {
  const void* x     = d_in[0];
  const void* ei    = d_in[1];
  const void* et    = d_in[2];
  const void* batch = d_in[3];
  const void* W1 = d_in[4],  *r1 = d_in[5],  *b1 = d_in[6];
  const void* W2 = d_in[7],  *r2 = d_in[8],  *b2 = d_in[9];
  const void* W3 = d_in[10], *r3 = d_in[11], *b3 = d_in[12];
  const void* g1 = d_in[13], *be1 = d_in[14];
  const void* g2 = d_in[15], *be2 = d_in[16];
  const void* A1 = d_in[17], *a1 = d_in[18];
  const void* A2 = d_in[19], *a2 = d_in[20];
  const void* C1 = d_in[21], *c1 = d_in[22];
  const void* C2 = d_in[23], *c2 = d_in[24];

  if (ws_size < WS_NEED){ k_wsfail<<<1, 1, 0, stream>>>((u32*)d_out); return; }
  char* ws = (char*)d_ws;
  float* out   = (float*)(ws + O_OUT);
  u16*   hbuf  = (u16*)(ws + O_H);
  u16*   xbf   = (u16*)(ws + O_XBF);
  u16*   wcat  = (u16*)(ws + O_WCAT);
  u16*   wext  = (u16*)(ws + O_WEXT);
  int*   ei_c  = (int*)(ws + O_EI);
  int*   et_c  = (int*)(ws + O_ET);
  int*   bat_c = (int*)(ws + O_BAT);
  u32*   src_s = (u32*)(ws + O_SRC);
  u32*   pairStart = (u32*)(ws + O_PST);
  float* gembC = (float*)(ws + O_GEMBC);
  u32*   cnt   = (u32*)(ws + O_CNT);
  float* sco   = (float*)(ws + O_SCO);
  float* aw    = (float*)(ws + O_AW);
  float* gemb  = (float*)(ws + O_GEMB);
  float* stats = (float*)(ws + O_STATS);
  u32*   misc  = (u32*)(ws + O_MISC);
  u16*   aggb  = (u16*)(ws + O_AGG);
  u32* cursor    = (u32*)(ws + O_OUT);
  u32* blockSum  = (u32*)(ws + O_OUT + 1600000);
  u32* blockBase = (u32*)(ws + O_OUT + 1604096);
  u32* smax = misc + 25;
  float* ssum = (float*)(misc + 26);
  u32* flags = misc + 27;
  u32* md = misc + 28;

  hipMemsetAsync(ws + O_CNT, 0, 1600000, stream);
  hipMemsetAsync(ws + O_GEMB, 0, 32768 + 2048 + 256, stream);

  k_detect<<<2, 256, 0, stream>>>(x, et, md);
  k_cvt<<<12305, 256, 0, stream>>>(ei, et, batch, x, ei_c, et_c, bat_c, xbf, cnt, md, flags);
  k_wprep<<<1955, 256, 0, stream>>>(W1, r1, W2, r2, W3, r3,
                                    A1, a1, A2, a2, C1, c1, C2, c2, wcat, wext, md, flags);

  k_pairA<<<PAIR_B, 256, 0, stream>>>(cnt, blockSum);
  k_pairB<<<1, 64, 0, stream>>>(blockSum, blockBase);
  k_pairC<<<PAIR_B, 256, 0, stream>>>(cnt, blockBase, pairStart, cursor);
  k_sort3<<<(EE + 255) / 256, 256, 0, stream>>>(ei_c, et_c, pairStart, cursor, src_s);

  const void* bias[3] = {b1, b2, b3};
  const void* gam[2] = {g1, g2};
  const void* bet[2] = {be1, be2};
  const u16* hin = xbf;
  for (int L = 0; L < 3; L++){
    const u16* wT = wcat + (size_t)L * 128 * 1152;
    k_agg<<<(NN + 3) / 4, 256, 0, stream>>>(hin, pairStart, src_s, aggb);
    k_gemm_big<<<1568, 256, 0, stream>>>(hin, aggb, wT, bias[L], out, md,
                                         stats + (L < 2 ? L * 256 : 0), (L < 2) ? 1 : 0,
                                         (L == 2) ? xbf : (u16*)nullptr);
    if (L < 2){
      k_bnapply<<<6250, 256, 0, stream>>>(out, stats + L * 256, gam[L], bet[L], hbuf, md, flags, 4u << L);
      hin = hbuf;
    }
  }
  k_scores_mfma<<<(NN + 63) / 64, 256, 0, stream>>>(xbf, wext, sco, smax);
  k_expsum<<<128, 256, 0, stream>>>(sco, smax, aw, ssum, flags);
  k_pool<<<(NN + POOL_CHUNK - 1) / POOL_CHUNK, 128, 0, stream>>>(out, aw, ssum, bat_c, gemb, flags);
  k_gembC<<<32, 256, 0, stream>>>(gemb, wext, gembC);
  k_final_mfma<<<(NN + 63) / 64, 256, 0, stream>>>(xbf, gembC, bat_c, wext, d_out, md,
                                                   pairStart, flags);
}